// Round 1
// baseline (1149.879 us; speedup 1.0000x reference)
//
#include <hip/hip_runtime.h>
#include <hip/hip_bf16.h>
#include <stdint.h>

typedef __attribute__((ext_vector_type(8))) __bf16 bf16x8;
typedef __attribute__((ext_vector_type(4))) __bf16 bf16x4;
typedef __attribute__((ext_vector_type(4))) float f32x4;

static constexpr int NN = 50000;
static constexpr int NE = 800000;
static constexpr int FX = 64;
static constexpr int FE = 32;
static constexpr int H  = 128;
static constexpr int NG = 128;
static constexpr int OD = 8;

// ---------------- conversion kernels ----------------
__global__ void cvt_f32_bf16(const float* __restrict__ in, __bf16* __restrict__ out, int n) {
  int idx = (blockIdx.x * blockDim.x + threadIdx.x) * 4;
  if (idx + 3 < n) {
    float4 v = *reinterpret_cast<const float4*>(in + idx);
    bf16x4 o;
    o[0] = (__bf16)v.x; o[1] = (__bf16)v.y; o[2] = (__bf16)v.z; o[3] = (__bf16)v.w;
    *reinterpret_cast<bf16x4*>(out + idx) = o;
  } else {
    for (; idx < n; ++idx) out[idx] = (__bf16)in[idx];
  }
}

// w: [K][128] f32 -> wt: [128][K] bf16 (N-major so B fragments are contiguous in k)
__global__ void cvt_w_t(const float* __restrict__ w, __bf16* __restrict__ wt, int K) {
  int i = blockIdx.x * blockDim.x + threadIdx.x;
  if (i >= K * 128) return;
  int n = i / K, k = i % K;
  wt[i] = (__bf16)w[k * 128 + n];
}

__global__ void relu_cvt(const float* __restrict__ agg, __bf16* __restrict__ h, int n) {
  int idx = (blockIdx.x * blockDim.x + threadIdx.x) * 4;
  if (idx + 3 < n) {
    float4 v = *reinterpret_cast<const float4*>(agg + idx);
    bf16x4 o;
    o[0] = (__bf16)fmaxf(v.x, 0.f); o[1] = (__bf16)fmaxf(v.y, 0.f);
    o[2] = (__bf16)fmaxf(v.z, 0.f); o[3] = (__bf16)fmaxf(v.w, 0.f);
    *reinterpret_cast<bf16x4*>(h + idx) = o;
  }
}

// ---------------- fused edge MLP + scatter ----------------
// Per block: 64 edges. GEMM1: [64, DIN] @ [DIN, 128], relu -> GEMM2: [64,128] @ [128,128]
// 4 waves, each owns a 32-col slice of N=128.
template<int DIN>
__global__ __launch_bounds__(256) void edge_mlp(
    const __bf16* __restrict__ hin,   // [NN][DIN-32]
    const __bf16* __restrict__ eat,   // [NE][32]
    const int* __restrict__ src, const int* __restrict__ dst,
    const __bf16* __restrict__ w1t,   // [128][DIN]
    const float* __restrict__ b1,     // [128]
    const __bf16* __restrict__ w2t,   // [128][128]
    const float* __restrict__ b2,     // [128]
    float* __restrict__ agg)          // [NN][128] fp32, atomic accumulate
{
  constexpr int F   = DIN - 32;
  constexpr int KS1 = DIN / 32;
  constexpr int APAD = DIN + 8;   // +16B pad breaks bank-conflict stride
  constexpr int MPAD = H + 8;

  __shared__ __bf16 As[64][APAD];
  __shared__ __bf16 Mid[64][MPAD];
  __shared__ int dst_s[64];

  const int tid  = threadIdx.x;
  const int lane = tid & 63;
  const int w    = tid >> 6;      // wave 0..3
  const int e0   = blockIdx.x * 64;

  const int colq = lane & 15;          // col within 16-tile
  const int krow = (lane >> 4) * 8;    // k offset within 32-k step
  const int rbase = (lane >> 4) * 4;   // C/D row base

  // ---- B fragments from pre-transposed weights (L2-resident) ----
  bf16x8 b1f[2][KS1];
  bf16x8 b2f[2][4];
#pragma unroll
  for (int nt = 0; nt < 2; ++nt) {
    const int col = w * 32 + nt * 16 + colq;
#pragma unroll
    for (int ks = 0; ks < KS1; ++ks)
      b1f[nt][ks] = *reinterpret_cast<const bf16x8*>(w1t + (size_t)col * DIN + ks * 32 + krow);
#pragma unroll
    for (int ks = 0; ks < 4; ++ks)
      b2f[nt][ks] = *reinterpret_cast<const bf16x8*>(w2t + (size_t)col * H + ks * 32 + krow);
  }

  // ---- gather phase: h[src] || edge_attr into LDS ----
  if (tid < 64) dst_s[tid] = dst[e0 + tid];
  constexpr int CH = F / 8;               // 16B chunks per node row
  for (int i = tid; i < 64 * CH; i += 256) {
    int row = i / CH;
    int c   = i % CH;
    int s   = src[e0 + row];
    *reinterpret_cast<bf16x8*>(&As[row][c * 8]) =
        *reinterpret_cast<const bf16x8*>(hin + (size_t)s * F + c * 8);
  }
  {
    int row = tid >> 2, c = tid & 3;    // 64 rows x 4 chunks of 8
    *reinterpret_cast<bf16x8*>(&As[row][F + c * 8]) =
        *reinterpret_cast<const bf16x8*>(eat + (size_t)(e0 + row) * FE + c * 8);
  }
  __syncthreads();

  // ---- GEMM1 ----
  f32x4 acc[4][2];
#pragma unroll
  for (int mt = 0; mt < 4; ++mt)
#pragma unroll
    for (int nt = 0; nt < 2; ++nt) {
      acc[mt][nt][0] = 0.f; acc[mt][nt][1] = 0.f; acc[mt][nt][2] = 0.f; acc[mt][nt][3] = 0.f;
    }
#pragma unroll
  for (int ks = 0; ks < KS1; ++ks) {
#pragma unroll
    for (int mt = 0; mt < 4; ++mt) {
      bf16x8 a = *reinterpret_cast<const bf16x8*>(&As[mt * 16 + colq][ks * 32 + krow]);
      acc[mt][0] = __builtin_amdgcn_mfma_f32_16x16x32_bf16(a, b1f[0][ks], acc[mt][0], 0, 0, 0);
      acc[mt][1] = __builtin_amdgcn_mfma_f32_16x16x32_bf16(a, b1f[1][ks], acc[mt][1], 0, 0, 0);
    }
  }

  // bias + relu -> Mid (bf16)
#pragma unroll
  for (int nt = 0; nt < 2; ++nt) {
    const int col = w * 32 + nt * 16 + colq;
    const float bb = b1[col];
#pragma unroll
    for (int mt = 0; mt < 4; ++mt)
#pragma unroll
      for (int r = 0; r < 4; ++r)
        Mid[mt * 16 + rbase + r][col] = (__bf16)fmaxf(acc[mt][nt][r] + bb, 0.f);
  }
  __syncthreads();

  // ---- GEMM2 ----
  f32x4 acc2[4][2];
#pragma unroll
  for (int mt = 0; mt < 4; ++mt)
#pragma unroll
    for (int nt = 0; nt < 2; ++nt) {
      acc2[mt][nt][0] = 0.f; acc2[mt][nt][1] = 0.f; acc2[mt][nt][2] = 0.f; acc2[mt][nt][3] = 0.f;
    }
#pragma unroll
  for (int ks = 0; ks < 4; ++ks) {
#pragma unroll
    for (int mt = 0; mt < 4; ++mt) {
      bf16x8 a = *reinterpret_cast<const bf16x8*>(&Mid[mt * 16 + colq][ks * 32 + krow]);
      acc2[mt][0] = __builtin_amdgcn_mfma_f32_16x16x32_bf16(a, b2f[0][ks], acc2[mt][0], 0, 0, 0);
      acc2[mt][1] = __builtin_amdgcn_mfma_f32_16x16x32_bf16(a, b2f[1][ks], acc2[mt][1], 0, 0, 0);
    }
  }

  // ---- bias + atomic scatter-add to agg ----
#pragma unroll
  for (int nt = 0; nt < 2; ++nt) {
    const int col = w * 32 + nt * 16 + colq;
    const float bb = b2[col];
#pragma unroll
    for (int mt = 0; mt < 4; ++mt)
#pragma unroll
      for (int r = 0; r < 4; ++r) {
        int row = mt * 16 + rbase + r;
        atomicAdd(agg + (size_t)dst_s[row] * H + col, acc2[mt][nt][r] + bb);
      }
  }
}

// ---------------- pooling ----------------
__global__ void pool_kernel(const float* __restrict__ agg, const int* __restrict__ batch,
                            float* __restrict__ sums, float* __restrict__ cnts) {
  const int col = threadIdx.x & 127;
  const int sub = threadIdx.x >> 7;       // 0..1
  const int NB = 128;
  int n0 = blockIdx.x * NB + sub * (NB / 2);
  if (n0 >= NN) return;
  int n1 = n0 + NB / 2; if (n1 > NN) n1 = NN;
  float s = 0.f, c = 0.f;
  int g = batch[n0];
  for (int n = n0; n < n1; ++n) {
    int gn = batch[n];
    if (gn != g) {
      atomicAdd(&sums[g * H + col], s);
      if (col == 0) atomicAdd(&cnts[g], c);
      s = 0.f; c = 0.f; g = gn;
    }
    s += fmaxf(agg[(size_t)n * H + col], 0.f);   // last layer's relu fused here
    c += 1.f;
  }
  atomicAdd(&sums[g * H + col], s);
  if (col == 0) atomicAdd(&cnts[g], c);
}

__global__ void final_kernel(const float* __restrict__ sums, const float* __restrict__ cnts,
                             const float* __restrict__ lw, const float* __restrict__ lb,
                             float* __restrict__ out) {
  int idx = blockIdx.x * blockDim.x + threadIdx.x;
  if (idx >= NG * OD) return;
  int g = idx / OD, o = idx % OD;
  float inv = 1.f / fmaxf(cnts[g], 1.f);
  float s = 0.f;
#pragma unroll 8
  for (int k = 0; k < H; ++k)
    s += sums[g * H + k] * lw[k * OD + o];
  out[idx] = s * inv + lb[o];
}

// ---------------- launcher ----------------
extern "C" void kernel_launch(void* const* d_in, const int* in_sizes, int n_in,
                              void* d_out, int out_size, void* d_ws, size_t ws_size,
                              hipStream_t stream) {
  const float* x   = (const float*)d_in[0];
  const int*   ei  = (const int*)d_in[1];
  const float* ea  = (const float*)d_in[2];
  const int*   bat = (const int*)d_in[3];
  const float* w1[3] = {(const float*)d_in[4], (const float*)d_in[8],  (const float*)d_in[12]};
  const float* b1[3] = {(const float*)d_in[5], (const float*)d_in[9],  (const float*)d_in[13]};
  const float* w2[3] = {(const float*)d_in[6], (const float*)d_in[10], (const float*)d_in[14]};
  const float* b2[3] = {(const float*)d_in[7], (const float*)d_in[11], (const float*)d_in[15]};
  const float* lw  = (const float*)d_in[16];
  const float* lb  = (const float*)d_in[17];
  float* out = (float*)d_out;

  char* ws = (char*)d_ws;
  size_t off = 0;
  auto alloc = [&](size_t bytes) -> void* {
    void* p = ws + off;
    off = (off + bytes + 255) & ~(size_t)255;
    return p;
  };
  __bf16* xb  = (__bf16*)alloc((size_t)NN * FX * 2);
  __bf16* hb  = (__bf16*)alloc((size_t)NN * H * 2);
  __bf16* eab = (__bf16*)alloc((size_t)NE * FE * 2);
  float*  agg = (float*) alloc((size_t)NN * H * 4);
  __bf16* w1t[3]; __bf16* w2t[3];
  for (int l = 0; l < 3; ++l) {
    w1t[l] = (__bf16*)alloc(128 * 160 * 2);
    w2t[l] = (__bf16*)alloc(128 * 128 * 2);
  }
  float* sums = (float*)alloc(NG * H * 4);
  float* cnts = (float*)alloc(NG * 4);

  const int* src = ei;
  const int* dst = ei + NE;

  cvt_f32_bf16<<<(NN * FX / 4 + 255) / 256, 256, 0, stream>>>(x, xb, NN * FX);
  cvt_f32_bf16<<<(NE * FE / 4 + 255) / 256, 256, 0, stream>>>(ea, eab, NE * FE);
  const int dins[3] = {96, 160, 160};
  for (int l = 0; l < 3; ++l) {
    cvt_w_t<<<(dins[l] * 128 + 255) / 256, 256, 0, stream>>>(w1[l], w1t[l], dins[l]);
    cvt_w_t<<<(128 * 128 + 255) / 256, 256, 0, stream>>>(w2[l], w2t[l], 128);
  }

  for (int l = 0; l < 3; ++l) {
    hipMemsetAsync(agg, 0, (size_t)NN * H * 4, stream);
    if (l == 0)
      edge_mlp<96><<<NE / 64, 256, 0, stream>>>(xb, eab, src, dst, w1t[0], b1[0], w2t[0], b2[0], agg);
    else
      edge_mlp<160><<<NE / 64, 256, 0, stream>>>(hb, eab, src, dst, w1t[l], b1[l], w2t[l], b2[l], agg);
    if (l < 2)
      relu_cvt<<<(NN * H / 4 + 255) / 256, 256, 0, stream>>>(agg, hb, NN * H);
  }

  hipMemsetAsync(sums, 0, NG * H * 4, stream);
  hipMemsetAsync(cnts, 0, NG * 4, stream);
  pool_kernel<<<(NN + 127) / 128, 256, 0, stream>>>(agg, bat, sums, cnts);
  final_kernel<<<(NG * OD + 255) / 256, 256, 0, stream>>>(sums, cnts, lw, lb, out);
}

// Round 2
// 722.047 us; speedup vs baseline: 1.5925x; 1.5925x over previous
//
#include <hip/hip_runtime.h>
#include <hip/hip_bf16.h>
#include <stdint.h>

typedef __attribute__((ext_vector_type(8))) __bf16 bf16x8;
typedef __attribute__((ext_vector_type(4))) __bf16 bf16x4;
typedef __attribute__((ext_vector_type(4))) float f32x4;

static constexpr int NN = 50000;
static constexpr int NE = 800000;
static constexpr int FX = 64;
static constexpr int FE = 32;
static constexpr int H  = 128;
static constexpr int NG = 128;
static constexpr int OD = 8;

// ---------------- conversion kernels ----------------
__global__ void cvt_f32_bf16(const float* __restrict__ in, __bf16* __restrict__ out, int n) {
  int idx = (blockIdx.x * blockDim.x + threadIdx.x) * 4;
  if (idx + 3 < n) {
    float4 v = *reinterpret_cast<const float4*>(in + idx);
    bf16x4 o;
    o[0] = (__bf16)v.x; o[1] = (__bf16)v.y; o[2] = (__bf16)v.z; o[3] = (__bf16)v.w;
    *reinterpret_cast<bf16x4*>(out + idx) = o;
  } else {
    for (; idx < n; ++idx) out[idx] = (__bf16)in[idx];
  }
}

// w: [K][128] f32 -> wt: [128][K] bf16
__global__ void cvt_w_t(const float* __restrict__ w, __bf16* __restrict__ wt, int K) {
  int i = blockIdx.x * blockDim.x + threadIdx.x;
  if (i >= K * 128) return;
  int n = i / K, k = i % K;
  wt[i] = (__bf16)w[k * 128 + n];
}

__global__ void relu_cvt(const float* __restrict__ agg, __bf16* __restrict__ h, int n) {
  int idx = (blockIdx.x * blockDim.x + threadIdx.x) * 4;
  if (idx + 3 < n) {
    float4 v = *reinterpret_cast<const float4*>(agg + idx);
    bf16x4 o;
    o[0] = (__bf16)fmaxf(v.x, 0.f); o[1] = (__bf16)fmaxf(v.y, 0.f);
    o[2] = (__bf16)fmaxf(v.z, 0.f); o[3] = (__bf16)fmaxf(v.w, 0.f);
    *reinterpret_cast<bf16x4*>(h + idx) = o;
  }
}

// ---------------- counting sort of edges by dst ----------------
__global__ void hist_build(const int* __restrict__ dst, int* __restrict__ hist) {
  int e = blockIdx.x * blockDim.x + threadIdx.x;
  if (e < NE) atomicAdd(&hist[dst[e]], 1);
}

__global__ void scan1(const int* __restrict__ hist, int* __restrict__ excl, int* __restrict__ btot) {
  __shared__ int tmp[256];
  int t = threadIdx.x;
  int i = blockIdx.x * 256 + t;
  int v = (i < NN) ? hist[i] : 0;
  tmp[t] = v;
  __syncthreads();
  for (int off = 1; off < 256; off <<= 1) {
    int add = (t >= off) ? tmp[t - off] : 0;
    __syncthreads();
    tmp[t] += add;
    __syncthreads();
  }
  if (i < NN) excl[i] = tmp[t] - v;
  if (t == 255) btot[blockIdx.x] = tmp[255];
}

__global__ void scan2(int* __restrict__ btot, int nb) {
  __shared__ int tmp[256];
  int t = threadIdx.x;
  int v = (t < nb) ? btot[t] : 0;
  tmp[t] = v;
  __syncthreads();
  for (int off = 1; off < 256; off <<= 1) {
    int add = (t >= off) ? tmp[t - off] : 0;
    __syncthreads();
    tmp[t] += add;
    __syncthreads();
  }
  if (t < nb) btot[t] = tmp[t] - v;
}

__global__ void scan3(const int* __restrict__ excl, const int* __restrict__ btot,
                      int* __restrict__ cursor) {
  int i = blockIdx.x * 256 + threadIdx.x;
  if (i < NN) cursor[i] = excl[i] + btot[blockIdx.x];
}

__global__ void scatter_perm(const int* __restrict__ src, const int* __restrict__ dst,
                             int* __restrict__ cursor,
                             int* __restrict__ srcp, int* __restrict__ dstp,
                             int* __restrict__ eperm) {
  int e = blockIdx.x * blockDim.x + threadIdx.x;
  if (e >= NE) return;
  int d = dst[e];
  int p = atomicAdd(&cursor[d], 1);
  srcp[p] = src[e];
  dstp[p] = d;
  eperm[p] = e;
}

// ---------------- fused edge MLP + segment-reduced scatter ----------------
// 64 dst-sorted edges per block; 4 waves each own a 32-col slice of N=128.
template<int DIN>
__global__ __launch_bounds__(256) void edge_mlp(
    const __bf16* __restrict__ hin,   // [NN][DIN-32]
    const __bf16* __restrict__ eat,   // [NE][32] (original order)
    const int* __restrict__ srcp,     // permuted src
    const int* __restrict__ dstp,     // sorted dst
    const int* __restrict__ eperm,    // permuted original edge id
    const __bf16* __restrict__ w1t,   // [128][DIN]
    const float* __restrict__ b1,
    const __bf16* __restrict__ w2t,   // [128][128]
    const float* __restrict__ b2,
    float* __restrict__ agg)          // [NN][128] fp32
{
  constexpr int F    = DIN - 32;
  constexpr int KS1  = DIN / 32;
  constexpr int APAD = DIN + 8;
  constexpr int MPAD = H + 8;
  constexpr int OPAD = 132;
  constexpr int ABYTES = 64 * APAD * 2;
  constexpr int MBYTES = 64 * MPAD * 2;
  constexpr int OBYTES = 64 * OPAD * 4;
  constexpr int SBYTES = (ABYTES + MBYTES > OBYTES) ? (ABYTES + MBYTES) : OBYTES;

  __shared__ __align__(16) char smem[SBYTES];
  __shared__ int dst_s[64];
  auto As  = reinterpret_cast<__bf16 (*)[APAD]>(smem);
  auto Mid = reinterpret_cast<__bf16 (*)[MPAD]>(smem + ABYTES);
  auto Out = reinterpret_cast<float (*)[OPAD]>(smem);

  const int tid  = threadIdx.x;
  const int lane = tid & 63;
  const int w    = tid >> 6;
  const int e0   = blockIdx.x * 64;

  const int colq  = lane & 15;
  const int krow  = (lane >> 4) * 8;
  const int rbase = (lane >> 4) * 4;

  // B fragments (L2-resident weights)
  bf16x8 b1f[2][KS1];
  bf16x8 b2f[2][4];
#pragma unroll
  for (int nt = 0; nt < 2; ++nt) {
    const int col = w * 32 + nt * 16 + colq;
#pragma unroll
    for (int ks = 0; ks < KS1; ++ks)
      b1f[nt][ks] = *reinterpret_cast<const bf16x8*>(w1t + (size_t)col * DIN + ks * 32 + krow);
#pragma unroll
    for (int ks = 0; ks < 4; ++ks)
      b2f[nt][ks] = *reinterpret_cast<const bf16x8*>(w2t + (size_t)col * H + ks * 32 + krow);
  }

  // gather: h[srcp] || ea[eperm]
  if (tid < 64) dst_s[tid] = dstp[e0 + tid];
  constexpr int CH = F / 8;
  for (int i = tid; i < 64 * CH; i += 256) {
    int row = i / CH;
    int c   = i % CH;
    int s   = srcp[e0 + row];
    *reinterpret_cast<bf16x8*>(&As[row][c * 8]) =
        *reinterpret_cast<const bf16x8*>(hin + (size_t)s * F + c * 8);
  }
  {
    int row = tid >> 2, c = tid & 3;
    int e = eperm[e0 + row];
    *reinterpret_cast<bf16x8*>(&As[row][F + c * 8]) =
        *reinterpret_cast<const bf16x8*>(eat + (size_t)e * FE + c * 8);
  }
  __syncthreads();

  // GEMM1
  f32x4 acc[4][2];
#pragma unroll
  for (int mt = 0; mt < 4; ++mt)
#pragma unroll
    for (int nt = 0; nt < 2; ++nt)
      acc[mt][nt] = (f32x4){0.f, 0.f, 0.f, 0.f};
#pragma unroll
  for (int ks = 0; ks < KS1; ++ks) {
#pragma unroll
    for (int mt = 0; mt < 4; ++mt) {
      bf16x8 a = *reinterpret_cast<const bf16x8*>(&As[mt * 16 + colq][ks * 32 + krow]);
      acc[mt][0] = __builtin_amdgcn_mfma_f32_16x16x32_bf16(a, b1f[0][ks], acc[mt][0], 0, 0, 0);
      acc[mt][1] = __builtin_amdgcn_mfma_f32_16x16x32_bf16(a, b1f[1][ks], acc[mt][1], 0, 0, 0);
    }
  }

  // bias + relu -> Mid
#pragma unroll
  for (int nt = 0; nt < 2; ++nt) {
    const int col = w * 32 + nt * 16 + colq;
    const float bb = b1[col];
#pragma unroll
    for (int mt = 0; mt < 4; ++mt)
#pragma unroll
      for (int r = 0; r < 4; ++r)
        Mid[mt * 16 + rbase + r][col] = (__bf16)fmaxf(acc[mt][nt][r] + bb, 0.f);
  }
  __syncthreads();

  // GEMM2
  f32x4 acc2[4][2];
#pragma unroll
  for (int mt = 0; mt < 4; ++mt)
#pragma unroll
    for (int nt = 0; nt < 2; ++nt)
      acc2[mt][nt] = (f32x4){0.f, 0.f, 0.f, 0.f};
#pragma unroll
  for (int ks = 0; ks < 4; ++ks) {
#pragma unroll
    for (int mt = 0; mt < 4; ++mt) {
      bf16x8 a = *reinterpret_cast<const bf16x8*>(&Mid[mt * 16 + colq][ks * 32 + krow]);
      acc2[mt][0] = __builtin_amdgcn_mfma_f32_16x16x32_bf16(a, b2f[0][ks], acc2[mt][0], 0, 0, 0);
      acc2[mt][1] = __builtin_amdgcn_mfma_f32_16x16x32_bf16(a, b2f[1][ks], acc2[mt][1], 0, 0, 0);
    }
  }
  __syncthreads();   // all waves done reading As/Mid — safe to alias Out

  // bias -> Out (f32, LDS)
#pragma unroll
  for (int nt = 0; nt < 2; ++nt) {
    const int col = w * 32 + nt * 16 + colq;
    const float bb = b2[col];
#pragma unroll
    for (int mt = 0; mt < 4; ++mt)
#pragma unroll
      for (int r = 0; r < 4; ++r)
        Out[mt * 16 + rbase + r][col] = acc2[mt][nt][r] + bb;
  }
  __syncthreads();

  // segment reduce over sorted dst: one atomic per (segment, col)
  {
    const int col = tid & 127;
    const int r0  = (tid >> 7) * 32;
    float s = Out[r0][col];
    int d = dst_s[r0];
    for (int r = r0 + 1; r < r0 + 32; ++r) {
      int dn = dst_s[r];
      if (dn != d) {
        atomicAdd(agg + (size_t)d * H + col, s);
        s = 0.f;
        d = dn;
      }
      s += Out[r][col];
    }
    atomicAdd(agg + (size_t)d * H + col, s);
  }
}

// ---------------- pooling ----------------
__global__ void pool_kernel(const float* __restrict__ agg, const int* __restrict__ batch,
                            float* __restrict__ sums, float* __restrict__ cnts) {
  const int col = threadIdx.x & 127;
  const int sub = threadIdx.x >> 7;
  const int NB = 128;
  int n0 = blockIdx.x * NB + sub * (NB / 2);
  if (n0 >= NN) return;
  int n1 = n0 + NB / 2; if (n1 > NN) n1 = NN;
  float s = 0.f, c = 0.f;
  int g = batch[n0];
  for (int n = n0; n < n1; ++n) {
    int gn = batch[n];
    if (gn != g) {
      atomicAdd(&sums[g * H + col], s);
      if (col == 0) atomicAdd(&cnts[g], c);
      s = 0.f; c = 0.f; g = gn;
    }
    s += fmaxf(agg[(size_t)n * H + col], 0.f);
    c += 1.f;
  }
  atomicAdd(&sums[g * H + col], s);
  if (col == 0) atomicAdd(&cnts[g], c);
}

__global__ void final_kernel(const float* __restrict__ sums, const float* __restrict__ cnts,
                             const float* __restrict__ lw, const float* __restrict__ lb,
                             float* __restrict__ out) {
  int idx = blockIdx.x * blockDim.x + threadIdx.x;
  if (idx >= NG * OD) return;
  int g = idx / OD, o = idx % OD;
  float inv = 1.f / fmaxf(cnts[g], 1.f);
  float s = 0.f;
#pragma unroll 8
  for (int k = 0; k < H; ++k)
    s += sums[g * H + k] * lw[k * OD + o];
  out[idx] = s * inv + lb[o];
}

// ---------------- launcher ----------------
extern "C" void kernel_launch(void* const* d_in, const int* in_sizes, int n_in,
                              void* d_out, int out_size, void* d_ws, size_t ws_size,
                              hipStream_t stream) {
  const float* x   = (const float*)d_in[0];
  const int*   ei  = (const int*)d_in[1];
  const float* ea  = (const float*)d_in[2];
  const int*   bat = (const int*)d_in[3];
  const float* w1[3] = {(const float*)d_in[4], (const float*)d_in[8],  (const float*)d_in[12]};
  const float* b1[3] = {(const float*)d_in[5], (const float*)d_in[9],  (const float*)d_in[13]};
  const float* w2[3] = {(const float*)d_in[6], (const float*)d_in[10], (const float*)d_in[14]};
  const float* b2[3] = {(const float*)d_in[7], (const float*)d_in[11], (const float*)d_in[15]};
  const float* lw  = (const float*)d_in[16];
  const float* lb  = (const float*)d_in[17];
  float* out = (float*)d_out;

  char* ws = (char*)d_ws;
  size_t off = 0;
  auto alloc = [&](size_t bytes) -> void* {
    void* p = ws + off;
    off = (off + bytes + 255) & ~(size_t)255;
    return p;
  };
  __bf16* xb  = (__bf16*)alloc((size_t)NN * FX * 2);
  __bf16* hb  = (__bf16*)alloc((size_t)NN * H * 2);
  __bf16* eab = (__bf16*)alloc((size_t)NE * FE * 2);
  float*  agg = (float*) alloc((size_t)NN * H * 4);
  __bf16* w1t[3]; __bf16* w2t[3];
  for (int l = 0; l < 3; ++l) {
    w1t[l] = (__bf16*)alloc(128 * 160 * 2);
    w2t[l] = (__bf16*)alloc(128 * 128 * 2);
  }
  float* sums = (float*)alloc(NG * H * 4);
  float* cnts = (float*)alloc(NG * 4);
  int* hist   = (int*)alloc((size_t)NN * 4);
  int* excl   = (int*)alloc((size_t)NN * 4);
  int* btot   = (int*)alloc(256 * 4);
  int* cursor = (int*)alloc((size_t)NN * 4);
  int* srcp   = (int*)alloc((size_t)NE * 4);
  int* dstp   = (int*)alloc((size_t)NE * 4);
  int* eperm  = (int*)alloc((size_t)NE * 4);

  const int* src = ei;
  const int* dst = ei + NE;
  const int NB_SCAN = (NN + 255) / 256;   // 196

  // conversions
  cvt_f32_bf16<<<(NN * FX / 4 + 255) / 256, 256, 0, stream>>>(x, xb, NN * FX);
  cvt_f32_bf16<<<(NE * FE / 4 + 255) / 256, 256, 0, stream>>>(ea, eab, NE * FE);
  const int dins[3] = {96, 160, 160};
  for (int l = 0; l < 3; ++l) {
    cvt_w_t<<<(dins[l] * 128 + 255) / 256, 256, 0, stream>>>(w1[l], w1t[l], dins[l]);
    cvt_w_t<<<(128 * 128 + 255) / 256, 256, 0, stream>>>(w2[l], w2t[l], 128);
  }

  // counting sort by dst
  hipMemsetAsync(hist, 0, (size_t)NN * 4, stream);
  hist_build<<<(NE + 255) / 256, 256, 0, stream>>>(dst, hist);
  scan1<<<NB_SCAN, 256, 0, stream>>>(hist, excl, btot);
  scan2<<<1, 256, 0, stream>>>(btot, NB_SCAN);
  scan3<<<NB_SCAN, 256, 0, stream>>>(excl, btot, cursor);
  scatter_perm<<<(NE + 255) / 256, 256, 0, stream>>>(src, dst, cursor, srcp, dstp, eperm);

  // layers
  for (int l = 0; l < 3; ++l) {
    hipMemsetAsync(agg, 0, (size_t)NN * H * 4, stream);
    if (l == 0)
      edge_mlp<96><<<NE / 64, 256, 0, stream>>>(xb, eab, srcp, dstp, eperm,
                                                w1t[0], b1[0], w2t[0], b2[0], agg);
    else
      edge_mlp<160><<<NE / 64, 256, 0, stream>>>(hb, eab, srcp, dstp, eperm,
                                                 w1t[l], b1[l], w2t[l], b2[l], agg);
    if (l < 2)
      relu_cvt<<<(NN * H / 4 + 255) / 256, 256, 0, stream>>>(agg, hb, NN * H);
  }

  hipMemsetAsync(sums, 0, NG * H * 4, stream);
  hipMemsetAsync(cnts, 0, NG * 4, stream);
  pool_kernel<<<(NN + 127) / 128, 256, 0, stream>>>(agg, bat, sums, cnts);
  final_kernel<<<(NG * OD + 255) / 256, 256, 0, stream>>>(sums, cnts, lw, lb, out);
}

// Round 3
// 648.783 us; speedup vs baseline: 1.7724x; 1.1129x over previous
//
#include <hip/hip_runtime.h>
#include <hip/hip_bf16.h>
#include <stdint.h>

typedef __attribute__((ext_vector_type(8))) __bf16 bf16x8;
typedef __attribute__((ext_vector_type(4))) __bf16 bf16x4;
typedef __attribute__((ext_vector_type(4))) float f32x4;

static constexpr int NN = 50000;
static constexpr int NE = 800000;
static constexpr int FX = 64;
static constexpr int FE = 32;
static constexpr int H  = 128;
static constexpr int NG = 128;
static constexpr int OD = 8;

// ---------------- conversion kernels ----------------
__global__ void cvt_f32_bf16(const float* __restrict__ in, __bf16* __restrict__ out, int n) {
  int idx = (blockIdx.x * blockDim.x + threadIdx.x) * 4;
  if (idx + 3 < n) {
    float4 v = *reinterpret_cast<const float4*>(in + idx);
    bf16x4 o;
    o[0] = (__bf16)v.x; o[1] = (__bf16)v.y; o[2] = (__bf16)v.z; o[3] = (__bf16)v.w;
    *reinterpret_cast<bf16x4*>(out + idx) = o;
  } else {
    for (; idx < n; ++idx) out[idx] = (__bf16)in[idx];
  }
}

// w: [K][128] f32 -> wt: [128][K] bf16
__global__ void cvt_w_t(const float* __restrict__ w, __bf16* __restrict__ wt, int K) {
  int i = blockIdx.x * blockDim.x + threadIdx.x;
  if (i >= K * 128) return;
  int n = i / K, k = i % K;
  wt[i] = (__bf16)w[k * 128 + n];
}

__global__ void relu_cvt(const float* __restrict__ agg, __bf16* __restrict__ h, int n) {
  int idx = (blockIdx.x * blockDim.x + threadIdx.x) * 4;
  if (idx + 3 < n) {
    float4 v = *reinterpret_cast<const float4*>(agg + idx);
    bf16x4 o;
    o[0] = (__bf16)fmaxf(v.x, 0.f); o[1] = (__bf16)fmaxf(v.y, 0.f);
    o[2] = (__bf16)fmaxf(v.z, 0.f); o[3] = (__bf16)fmaxf(v.w, 0.f);
    *reinterpret_cast<bf16x4*>(h + idx) = o;
  }
}

// ---------------- counting sort of edges by dst ----------------
__global__ void hist_build(const int* __restrict__ dst, int* __restrict__ hist) {
  int e = blockIdx.x * blockDim.x + threadIdx.x;
  if (e < NE) atomicAdd(&hist[dst[e]], 1);
}

__global__ void scan1(const int* __restrict__ hist, int* __restrict__ excl, int* __restrict__ btot) {
  __shared__ int tmp[256];
  int t = threadIdx.x;
  int i = blockIdx.x * 256 + t;
  int v = (i < NN) ? hist[i] : 0;
  tmp[t] = v;
  __syncthreads();
  for (int off = 1; off < 256; off <<= 1) {
    int add = (t >= off) ? tmp[t - off] : 0;
    __syncthreads();
    tmp[t] += add;
    __syncthreads();
  }
  if (i < NN) excl[i] = tmp[t] - v;
  if (t == 255) btot[blockIdx.x] = tmp[255];
}

__global__ void scan2(int* __restrict__ btot, int nb) {
  __shared__ int tmp[256];
  int t = threadIdx.x;
  int v = (t < nb) ? btot[t] : 0;
  tmp[t] = v;
  __syncthreads();
  for (int off = 1; off < 256; off <<= 1) {
    int add = (t >= off) ? tmp[t - off] : 0;
    __syncthreads();
    tmp[t] += add;
    __syncthreads();
  }
  if (t < nb) btot[t] = tmp[t] - v;
}

__global__ void scan3(const int* __restrict__ excl, const int* __restrict__ btot,
                      int* __restrict__ cursor) {
  int i = blockIdx.x * 256 + threadIdx.x;
  if (i < NN) cursor[i] = excl[i] + btot[blockIdx.x];
}

__global__ void scatter_perm(const int* __restrict__ src, const int* __restrict__ dst,
                             int* __restrict__ cursor,
                             int* __restrict__ srcp, int* __restrict__ dstp,
                             int* __restrict__ eperm) {
  int e = blockIdx.x * blockDim.x + threadIdx.x;
  if (e >= NE) return;
  int d = dst[e];
  int p = atomicAdd(&cursor[d], 1);
  srcp[p] = src[e];
  dstp[p] = d;
  eperm[p] = e;
}

// edge_attr -> bf16, permuted to sorted order (one-time)
__global__ void sort_ea(const float* __restrict__ ea, const int* __restrict__ eperm,
                        __bf16* __restrict__ eabs) {
  int i = blockIdx.x * blockDim.x + threadIdx.x;
  if (i >= NE * 4) return;
  int p = i >> 2, c = i & 3;
  int e = eperm[p];
  float4 v0 = *reinterpret_cast<const float4*>(ea + (size_t)e * FE + c * 8);
  float4 v1 = *reinterpret_cast<const float4*>(ea + (size_t)e * FE + c * 8 + 4);
  bf16x8 o;
  o[0] = (__bf16)v0.x; o[1] = (__bf16)v0.y; o[2] = (__bf16)v0.z; o[3] = (__bf16)v0.w;
  o[4] = (__bf16)v1.x; o[5] = (__bf16)v1.y; o[6] = (__bf16)v1.z; o[7] = (__bf16)v1.w;
  *reinterpret_cast<bf16x8*>(eabs + (size_t)p * FE + c * 8) = o;
}

// ---------------- node-side GEMM: Y = h @ W1h (no bias) ----------------
// M=64 per block, 256 threads, 4 waves each owning a 32-col slice.
template<int F, int DIN>
__global__ __launch_bounds__(256) void node_gemm(
    const __bf16* __restrict__ A,    // [NN][F]
    const __bf16* __restrict__ wt,   // [128][DIN], h-part at col offset 0
    __bf16* __restrict__ Y)          // [NN][128]
{
  constexpr int APAD = F + 8;
  constexpr int KS   = F / 32;
  constexpr int CH   = F / 8;
  constexpr int AB   = 64 * APAD * 2;
  constexpr int OB   = 64 * 136 * 2;
  constexpr int SB   = (AB > OB) ? AB : OB;
  __shared__ __align__(16) char smem[SB];
  auto As  = reinterpret_cast<__bf16 (*)[APAD]>(smem);
  auto Ost = reinterpret_cast<__bf16 (*)[136]>(smem);

  const int tid  = threadIdx.x;
  const int lane = tid & 63;
  const int w    = tid >> 6;
  const int m0   = blockIdx.x * 64;
  const int colq  = lane & 15;
  const int krow  = (lane >> 4) * 8;
  const int rbase = (lane >> 4) * 4;

  bf16x8 bf[2][KS];
#pragma unroll
  for (int nt = 0; nt < 2; ++nt) {
    const int col = w * 32 + nt * 16 + colq;
#pragma unroll
    for (int ks = 0; ks < KS; ++ks)
      bf[nt][ks] = *reinterpret_cast<const bf16x8*>(wt + (size_t)col * DIN + ks * 32 + krow);
  }

  for (int i = tid; i < 64 * CH; i += 256) {
    int row = i / CH, c = i % CH;
    int g = m0 + row; if (g >= NN) g = NN - 1;
    *reinterpret_cast<bf16x8*>(&As[row][c * 8]) =
        *reinterpret_cast<const bf16x8*>(A + (size_t)g * F + c * 8);
  }
  __syncthreads();

  f32x4 acc[4][2];
#pragma unroll
  for (int mt = 0; mt < 4; ++mt)
#pragma unroll
    for (int nt = 0; nt < 2; ++nt)
      acc[mt][nt] = (f32x4){0.f, 0.f, 0.f, 0.f};
#pragma unroll
  for (int ks = 0; ks < KS; ++ks)
#pragma unroll
    for (int mt = 0; mt < 4; ++mt) {
      bf16x8 a = *reinterpret_cast<const bf16x8*>(&As[mt * 16 + colq][ks * 32 + krow]);
      acc[mt][0] = __builtin_amdgcn_mfma_f32_16x16x32_bf16(a, bf[0][ks], acc[mt][0], 0, 0, 0);
      acc[mt][1] = __builtin_amdgcn_mfma_f32_16x16x32_bf16(a, bf[1][ks], acc[mt][1], 0, 0, 0);
    }
  __syncthreads();   // done reading As; Ost aliases it

#pragma unroll
  for (int nt = 0; nt < 2; ++nt) {
    const int col = w * 32 + nt * 16 + colq;
#pragma unroll
    for (int mt = 0; mt < 4; ++mt)
#pragma unroll
      for (int r = 0; r < 4; ++r)
        Ost[mt * 16 + rbase + r][col] = (__bf16)acc[mt][nt][r];
  }
  __syncthreads();

  for (int i = tid; i < 64 * 16; i += 256) {
    int row = i >> 4, c = i & 15;
    int g = m0 + row;
    if (g < NN)
      *reinterpret_cast<bf16x8*>(Y + (size_t)g * H + c * 8) =
          *reinterpret_cast<const bf16x8*>(&Ost[row][c * 8]);
  }
}

// ---------------- fused edge kernel ----------------
// 128 dst-sorted edges per block, 512 threads = 8 waves (2 row-groups x 4 col-groups).
// Mid = relu(Y[src] + ea@W1e + b1); GEMM2 -> segment-reduced atomic scatter.
template<int DIN>
__global__ __launch_bounds__(512) void edge_mlp2(
    const __bf16* __restrict__ Yb,    // [NN][128]
    const __bf16* __restrict__ eabs,  // [NE][32] sorted
    const int* __restrict__ srcp, const int* __restrict__ dstp,
    const __bf16* __restrict__ w1t,   // [128][DIN]; e-part at col offset F
    const float* __restrict__ b1,
    const __bf16* __restrict__ w2t,   // [128][128]
    const float* __restrict__ b2,
    float* __restrict__ agg)          // [NN][128] fp32
{
  constexpr int F = DIN - 32;
  constexpr int AEB = 128 * 40 * 2;     // [128][40] bf16
  constexpr int MIB = 128 * 136 * 2;    // [128][136] bf16
  constexpr int OUB = 128 * 132 * 4;    // [128][132] f32
  constexpr int SB  = (AEB + MIB > OUB) ? (AEB + MIB) : OUB;

  __shared__ __align__(16) char smem[SB];
  __shared__ int dst_s[128];
  auto Ae  = reinterpret_cast<__bf16 (*)[40]>(smem);
  auto Mid = reinterpret_cast<__bf16 (*)[136]>(smem + AEB);
  auto Out = reinterpret_cast<float (*)[132]>(smem);

  const int tid  = threadIdx.x;
  const int lane = tid & 63;
  const int w    = tid >> 6;
  const int wr   = w >> 2;            // 0..1 : row group (64 rows)
  const int wc   = w & 3;             // 0..3 : col group (32 cols)
  const int e0   = blockIdx.x * 128;

  const int colq  = lane & 15;
  const int krow  = (lane >> 4) * 8;
  const int rbase = (lane >> 4) * 4;

  // ---- B fragments + biases ----
  bf16x8 b1f[2];
  bf16x8 b2f[2][4];
  float b1s[2], b2s[2];
#pragma unroll
  for (int nt = 0; nt < 2; ++nt) {
    const int col = wc * 32 + nt * 16 + colq;
    b1f[nt] = *reinterpret_cast<const bf16x8*>(w1t + (size_t)col * DIN + F + krow);
    b1s[nt] = b1[col];
    b2s[nt] = b2[col];
#pragma unroll
    for (int ks = 0; ks < 4; ++ks)
      b2f[nt][ks] = *reinterpret_cast<const bf16x8*>(w2t + (size_t)col * H + ks * 32 + krow);
  }

  // ---- stage: Ae (sorted ea) + gather Y[src] into Mid ----
  if (tid < 128) dst_s[tid] = dstp[e0 + tid];
  {
    int row = tid >> 2, c = tid & 3;
    *reinterpret_cast<bf16x8*>(&Ae[row][c * 8]) =
        *reinterpret_cast<const bf16x8*>(eabs + (size_t)(e0 + row) * FE + c * 8);
  }
  for (int i = tid; i < 128 * 16; i += 512) {
    int row = i >> 4, c = i & 15;
    int s = srcp[e0 + row];
    *reinterpret_cast<bf16x8*>(&Mid[row][c * 8]) =
        *reinterpret_cast<const bf16x8*>(Yb + (size_t)s * H + c * 8);
  }
  __syncthreads();

  // ---- GEMM1e: ea @ W1e, acc init = b1 ----
  f32x4 acc[4][2];
#pragma unroll
  for (int mt = 0; mt < 4; ++mt)
#pragma unroll
    for (int nt = 0; nt < 2; ++nt)
      acc[mt][nt] = (f32x4){b1s[nt], b1s[nt], b1s[nt], b1s[nt]};
#pragma unroll
  for (int mt = 0; mt < 4; ++mt) {
    bf16x8 a = *reinterpret_cast<const bf16x8*>(&Ae[wr * 64 + mt * 16 + colq][krow]);
    acc[mt][0] = __builtin_amdgcn_mfma_f32_16x16x32_bf16(a, b1f[0], acc[mt][0], 0, 0, 0);
    acc[mt][1] = __builtin_amdgcn_mfma_f32_16x16x32_bf16(a, b1f[1], acc[mt][1], 0, 0, 0);
  }

  // ---- RMW: Mid = relu(Mid + acc) on this wave's (row,col) region ----
#pragma unroll
  for (int mt = 0; mt < 4; ++mt)
#pragma unroll
    for (int nt = 0; nt < 2; ++nt) {
      const int col = wc * 32 + nt * 16 + colq;
#pragma unroll
      for (int r = 0; r < 4; ++r) {
        const int row = wr * 64 + mt * 16 + rbase + r;
        float v = (float)Mid[row][col] + acc[mt][nt][r];
        Mid[row][col] = (__bf16)fmaxf(v, 0.f);
      }
    }
  __syncthreads();

  // ---- GEMM2: Mid @ W2, acc init = b2 ----
  f32x4 acc2[4][2];
#pragma unroll
  for (int mt = 0; mt < 4; ++mt)
#pragma unroll
    for (int nt = 0; nt < 2; ++nt)
      acc2[mt][nt] = (f32x4){b2s[nt], b2s[nt], b2s[nt], b2s[nt]};
#pragma unroll
  for (int ks = 0; ks < 4; ++ks)
#pragma unroll
    for (int mt = 0; mt < 4; ++mt) {
      bf16x8 a = *reinterpret_cast<const bf16x8*>(&Mid[wr * 64 + mt * 16 + colq][ks * 32 + krow]);
      acc2[mt][0] = __builtin_amdgcn_mfma_f32_16x16x32_bf16(a, b2f[0][ks], acc2[mt][0], 0, 0, 0);
      acc2[mt][1] = __builtin_amdgcn_mfma_f32_16x16x32_bf16(a, b2f[1][ks], acc2[mt][1], 0, 0, 0);
    }
  __syncthreads();   // done reading Ae/Mid; Out aliases them

  // ---- Out (f32) ----
#pragma unroll
  for (int nt = 0; nt < 2; ++nt) {
    const int col = wc * 32 + nt * 16 + colq;
#pragma unroll
    for (int mt = 0; mt < 4; ++mt)
#pragma unroll
      for (int r = 0; r < 4; ++r)
        Out[wr * 64 + mt * 16 + rbase + r][col] = acc2[mt][nt][r];
  }
  __syncthreads();

  // ---- segment reduce over sorted dst ----
  {
    const int col = tid & 127;
    const int r0  = (tid >> 7) * 32;
    float s = Out[r0][col];
    int d = dst_s[r0];
    for (int r = r0 + 1; r < r0 + 32; ++r) {
      int dn = dst_s[r];
      if (dn != d) {
        atomicAdd(agg + (size_t)d * H + col, s);
        s = 0.f;
        d = dn;
      }
      s += Out[r][col];
    }
    atomicAdd(agg + (size_t)d * H + col, s);
  }
}

// ---------------- pooling ----------------
__global__ void pool_kernel(const float* __restrict__ agg, const int* __restrict__ batch,
                            float* __restrict__ sums, float* __restrict__ cnts) {
  const int col = threadIdx.x & 127;
  const int sub = threadIdx.x >> 7;
  const int NB = 128;
  int n0 = blockIdx.x * NB + sub * (NB / 2);
  if (n0 >= NN) return;
  int n1 = n0 + NB / 2; if (n1 > NN) n1 = NN;
  float s = 0.f, c = 0.f;
  int g = batch[n0];
  for (int n = n0; n < n1; ++n) {
    int gn = batch[n];
    if (gn != g) {
      atomicAdd(&sums[g * H + col], s);
      if (col == 0) atomicAdd(&cnts[g], c);
      s = 0.f; c = 0.f; g = gn;
    }
    s += fmaxf(agg[(size_t)n * H + col], 0.f);
    c += 1.f;
  }
  atomicAdd(&sums[g * H + col], s);
  if (col == 0) atomicAdd(&cnts[g], c);
}

__global__ void final_kernel(const float* __restrict__ sums, const float* __restrict__ cnts,
                             const float* __restrict__ lw, const float* __restrict__ lb,
                             float* __restrict__ out) {
  int idx = blockIdx.x * blockDim.x + threadIdx.x;
  if (idx >= NG * OD) return;
  int g = idx / OD, o = idx % OD;
  float inv = 1.f / fmaxf(cnts[g], 1.f);
  float s = 0.f;
#pragma unroll 8
  for (int k = 0; k < H; ++k)
    s += sums[g * H + k] * lw[k * OD + o];
  out[idx] = s * inv + lb[o];
}

// ---------------- launcher ----------------
extern "C" void kernel_launch(void* const* d_in, const int* in_sizes, int n_in,
                              void* d_out, int out_size, void* d_ws, size_t ws_size,
                              hipStream_t stream) {
  const float* x   = (const float*)d_in[0];
  const int*   ei  = (const int*)d_in[1];
  const float* ea  = (const float*)d_in[2];
  const int*   bat = (const int*)d_in[3];
  const float* w1[3] = {(const float*)d_in[4], (const float*)d_in[8],  (const float*)d_in[12]};
  const float* b1[3] = {(const float*)d_in[5], (const float*)d_in[9],  (const float*)d_in[13]};
  const float* w2[3] = {(const float*)d_in[6], (const float*)d_in[10], (const float*)d_in[14]};
  const float* b2[3] = {(const float*)d_in[7], (const float*)d_in[11], (const float*)d_in[15]};
  const float* lw  = (const float*)d_in[16];
  const float* lb  = (const float*)d_in[17];
  float* out = (float*)d_out;

  char* ws = (char*)d_ws;
  size_t off = 0;
  auto alloc = [&](size_t bytes) -> void* {
    void* p = ws + off;
    off = (off + bytes + 255) & ~(size_t)255;
    return p;
  };
  __bf16* xb   = (__bf16*)alloc((size_t)NN * FX * 2);
  __bf16* hb   = (__bf16*)alloc((size_t)NN * H * 2);
  __bf16* Yb   = (__bf16*)alloc((size_t)NN * H * 2);
  __bf16* eabs = (__bf16*)alloc((size_t)NE * FE * 2);
  float*  agg  = (float*) alloc((size_t)NN * H * 4);
  __bf16* w1t[3]; __bf16* w2t[3];
  for (int l = 0; l < 3; ++l) {
    w1t[l] = (__bf16*)alloc(128 * 160 * 2);
    w2t[l] = (__bf16*)alloc(128 * 128 * 2);
  }
  float* sums = (float*)alloc(NG * H * 4);
  float* cnts = (float*)alloc(NG * 4);
  int* hist   = (int*)alloc((size_t)NN * 4);
  int* excl   = (int*)alloc((size_t)NN * 4);
  int* btot   = (int*)alloc(256 * 4);
  int* cursor = (int*)alloc((size_t)NN * 4);
  int* srcp   = (int*)alloc((size_t)NE * 4);
  int* dstp   = (int*)alloc((size_t)NE * 4);
  int* eperm  = (int*)alloc((size_t)NE * 4);

  const int* src = ei;
  const int* dst = ei + NE;
  const int NB_SCAN = (NN + 255) / 256;

  // conversions
  cvt_f32_bf16<<<(NN * FX / 4 + 255) / 256, 256, 0, stream>>>(x, xb, NN * FX);
  const int dins[3] = {96, 160, 160};
  for (int l = 0; l < 3; ++l) {
    cvt_w_t<<<(dins[l] * 128 + 255) / 256, 256, 0, stream>>>(w1[l], w1t[l], dins[l]);
    cvt_w_t<<<(128 * 128 + 255) / 256, 256, 0, stream>>>(w2[l], w2t[l], 128);
  }

  // counting sort by dst + sorted bf16 edge_attr
  hipMemsetAsync(hist, 0, (size_t)NN * 4, stream);
  hist_build<<<(NE + 255) / 256, 256, 0, stream>>>(dst, hist);
  scan1<<<NB_SCAN, 256, 0, stream>>>(hist, excl, btot);
  scan2<<<1, 256, 0, stream>>>(btot, NB_SCAN);
  scan3<<<NB_SCAN, 256, 0, stream>>>(excl, btot, cursor);
  scatter_perm<<<(NE + 255) / 256, 256, 0, stream>>>(src, dst, cursor, srcp, dstp, eperm);
  sort_ea<<<(NE * 4 + 255) / 256, 256, 0, stream>>>(ea, eperm, eabs);

  // layers
  for (int l = 0; l < 3; ++l) {
    if (l == 0)
      node_gemm<64, 96><<<(NN + 63) / 64, 256, 0, stream>>>(xb, w1t[0], Yb);
    else
      node_gemm<128, 160><<<(NN + 63) / 64, 256, 0, stream>>>(hb, w1t[l], Yb);

    hipMemsetAsync(agg, 0, (size_t)NN * H * 4, stream);
    if (l == 0)
      edge_mlp2<96><<<NE / 128, 512, 0, stream>>>(Yb, eabs, srcp, dstp,
                                                  w1t[0], b1[0], w2t[0], b2[0], agg);
    else
      edge_mlp2<160><<<NE / 128, 512, 0, stream>>>(Yb, eabs, srcp, dstp,
                                                   w1t[l], b1[l], w2t[l], b2[l], agg);
    if (l < 2)
      relu_cvt<<<(NN * H / 4 + 255) / 256, 256, 0, stream>>>(agg, hb, NN * H);
  }

  hipMemsetAsync(sums, 0, NG * H * 4, stream);
  hipMemsetAsync(cnts, 0, NG * 4, stream);
  pool_kernel<<<(NN + 127) / 128, 256, 0, stream>>>(agg, bat, sums, cnts);
  final_kernel<<<(NG * OD + 255) / 256, 256, 0, stream>>>(sums, cnts, lw, lb, out);
}

// Round 4
// 561.688 us; speedup vs baseline: 2.0472x; 1.1551x over previous
//
#include <hip/hip_runtime.h>
#include <hip/hip_bf16.h>
#include <stdint.h>

typedef __attribute__((ext_vector_type(8))) __bf16 bf16x8;
typedef __attribute__((ext_vector_type(4))) __bf16 bf16x4;
typedef __attribute__((ext_vector_type(4))) float f32x4;

static constexpr int NN = 50000;
static constexpr int NE = 800000;
static constexpr int FX = 64;
static constexpr int FE = 32;
static constexpr int H  = 128;
static constexpr int NG = 128;
static constexpr int OD = 8;

// ---------------- conversion kernels ----------------
__global__ void cvt_f32_bf16(const float* __restrict__ in, __bf16* __restrict__ out, int n) {
  int idx = (blockIdx.x * blockDim.x + threadIdx.x) * 4;
  if (idx + 3 < n) {
    float4 v = *reinterpret_cast<const float4*>(in + idx);
    bf16x4 o;
    o[0] = (__bf16)v.x; o[1] = (__bf16)v.y; o[2] = (__bf16)v.z; o[3] = (__bf16)v.w;
    *reinterpret_cast<bf16x4*>(out + idx) = o;
  } else {
    for (; idx < n; ++idx) out[idx] = (__bf16)in[idx];
  }
}

// w: [K][128] f32 -> wt: [128][K] bf16
__global__ void cvt_w_t(const float* __restrict__ w, __bf16* __restrict__ wt, int K) {
  int i = blockIdx.x * blockDim.x + threadIdx.x;
  if (i >= K * 128) return;
  int n = i / K, k = i % K;
  wt[i] = (__bf16)w[k * 128 + n];
}

// ---------------- counting sort of edges by dst ----------------
__global__ void hist_build(const int* __restrict__ dst, int* __restrict__ hist) {
  int e = blockIdx.x * blockDim.x + threadIdx.x;
  if (e < NE) atomicAdd(&hist[dst[e]], 1);
}

__global__ void scan1(const int* __restrict__ hist, int* __restrict__ excl, int* __restrict__ btot) {
  __shared__ int tmp[256];
  int t = threadIdx.x;
  int i = blockIdx.x * 256 + t;
  int v = (i < NN) ? hist[i] : 0;
  tmp[t] = v;
  __syncthreads();
  for (int off = 1; off < 256; off <<= 1) {
    int add = (t >= off) ? tmp[t - off] : 0;
    __syncthreads();
    tmp[t] += add;
    __syncthreads();
  }
  if (i < NN) excl[i] = tmp[t] - v;
  if (t == 255) btot[blockIdx.x] = tmp[255];
}

__global__ void scan2(int* __restrict__ btot, int nb) {
  __shared__ int tmp[256];
  int t = threadIdx.x;
  int v = (t < nb) ? btot[t] : 0;
  tmp[t] = v;
  __syncthreads();
  for (int off = 1; off < 256; off <<= 1) {
    int add = (t >= off) ? tmp[t - off] : 0;
    __syncthreads();
    tmp[t] += add;
    __syncthreads();
  }
  if (t < nb) btot[t] = tmp[t] - v;
}

__global__ void scan3(const int* __restrict__ excl, const int* __restrict__ btot,
                      int* __restrict__ cursor) {
  int i = blockIdx.x * 256 + threadIdx.x;
  if (i < NN) cursor[i] = excl[i] + btot[blockIdx.x];
}

__global__ void scatter_perm(const int* __restrict__ src, const int* __restrict__ dst,
                             int* __restrict__ cursor,
                             int* __restrict__ srcp, int* __restrict__ dstp,
                             int* __restrict__ eperm) {
  int e = blockIdx.x * blockDim.x + threadIdx.x;
  if (e >= NE) return;
  int d = dst[e];
  int p = atomicAdd(&cursor[d], 1);
  srcp[p] = src[e];
  dstp[p] = d;
  eperm[p] = e;
}

// edge_attr -> bf16, permuted to sorted order (one-time)
__global__ void sort_ea(const float* __restrict__ ea, const int* __restrict__ eperm,
                        __bf16* __restrict__ eabs) {
  int i = blockIdx.x * blockDim.x + threadIdx.x;
  if (i >= NE * 4) return;
  int p = i >> 2, c = i & 3;
  int e = eperm[p];
  float4 v0 = *reinterpret_cast<const float4*>(ea + (size_t)e * FE + c * 8);
  float4 v1 = *reinterpret_cast<const float4*>(ea + (size_t)e * FE + c * 8 + 4);
  bf16x8 o;
  o[0] = (__bf16)v0.x; o[1] = (__bf16)v0.y; o[2] = (__bf16)v0.z; o[3] = (__bf16)v0.w;
  o[4] = (__bf16)v1.x; o[5] = (__bf16)v1.y; o[6] = (__bf16)v1.z; o[7] = (__bf16)v1.w;
  *reinterpret_cast<bf16x8*>(eabs + (size_t)p * FE + c * 8) = o;
}

// ---------------- node-side GEMM: Y = act(A) @ W1h ----------------
// 128 rows/block, 512 threads, 8 waves each owning a 16-col slice.
// F32IN: input is fp32 agg, apply relu inline (fuses old relu_cvt).
template<int F, int DIN, bool F32IN>
__global__ __launch_bounds__(512) void node_gemm2(
    const void* __restrict__ Ain,
    const __bf16* __restrict__ wt,   // [128][DIN], h-part at col offset 0
    __bf16* __restrict__ Y)          // [NN][128]
{
  constexpr int APAD = F + 8;
  constexpr int KS   = F / 32;
  constexpr int CH   = F / 8;
  constexpr int AB   = 128 * APAD * 2;
  constexpr int OB   = 128 * 136 * 2;
  constexpr int SB   = (AB > OB) ? AB : OB;
  __shared__ __align__(16) char smem[SB];
  auto As  = reinterpret_cast<__bf16 (*)[APAD]>(smem);
  auto Ost = reinterpret_cast<__bf16 (*)[136]>(smem);

  const int tid   = threadIdx.x;
  const int lane  = tid & 63;
  const int w     = tid >> 6;
  const int m0    = blockIdx.x * 128;
  const int colq  = lane & 15;
  const int krow  = (lane >> 4) * 8;
  const int rbase = (lane >> 4) * 4;
  const int col   = w * 16 + colq;

  bf16x8 bf[KS];
#pragma unroll
  for (int ks = 0; ks < KS; ++ks)
    bf[ks] = *reinterpret_cast<const bf16x8*>(wt + (size_t)col * DIN + ks * 32 + krow);

  for (int i = tid; i < 128 * CH; i += 512) {
    int row = i / CH, c = i % CH;
    int g = m0 + row; if (g >= NN) g = NN - 1;
    if (F32IN) {
      const float* s = (const float*)Ain + (size_t)g * F + c * 8;
      float4 v0 = *reinterpret_cast<const float4*>(s);
      float4 v1 = *reinterpret_cast<const float4*>(s + 4);
      bf16x8 o;
      o[0] = (__bf16)fmaxf(v0.x, 0.f); o[1] = (__bf16)fmaxf(v0.y, 0.f);
      o[2] = (__bf16)fmaxf(v0.z, 0.f); o[3] = (__bf16)fmaxf(v0.w, 0.f);
      o[4] = (__bf16)fmaxf(v1.x, 0.f); o[5] = (__bf16)fmaxf(v1.y, 0.f);
      o[6] = (__bf16)fmaxf(v1.z, 0.f); o[7] = (__bf16)fmaxf(v1.w, 0.f);
      *reinterpret_cast<bf16x8*>(&As[row][c * 8]) = o;
    } else {
      *reinterpret_cast<bf16x8*>(&As[row][c * 8]) =
          *reinterpret_cast<const bf16x8*>((const __bf16*)Ain + (size_t)g * F + c * 8);
    }
  }
  __syncthreads();

  f32x4 acc[8];
#pragma unroll
  for (int mt = 0; mt < 8; ++mt) acc[mt] = (f32x4){0.f, 0.f, 0.f, 0.f};
#pragma unroll
  for (int ks = 0; ks < KS; ++ks)
#pragma unroll
    for (int mt = 0; mt < 8; ++mt) {
      bf16x8 a = *reinterpret_cast<const bf16x8*>(&As[mt * 16 + colq][ks * 32 + krow]);
      acc[mt] = __builtin_amdgcn_mfma_f32_16x16x32_bf16(a, bf[ks], acc[mt], 0, 0, 0);
    }
  __syncthreads();   // done reading As; Ost aliases it

#pragma unroll
  for (int mt = 0; mt < 8; ++mt)
#pragma unroll
    for (int r = 0; r < 4; ++r)
      Ost[mt * 16 + rbase + r][col] = (__bf16)acc[mt][r];
  __syncthreads();

  for (int i = tid; i < 128 * 16; i += 512) {
    int row = i >> 4, c = i & 15;
    int g = m0 + row;
    if (g < NN)
      *reinterpret_cast<bf16x8*>(Y + (size_t)g * H + c * 8) =
          *reinterpret_cast<const bf16x8*>(&Ost[row][c * 8]);
  }
}

// ---------------- fused edge kernel, multi-tile pipelined ----------------
// Each block: TPB tiles of 128 dst-sorted edges. 512 threads = 8 waves, each
// owning a 16-col slice x all 128 rows. Tile t+1's gathers are issued into
// registers while tile t computes.
template<int DIN>
__global__ __launch_bounds__(512, 4) void edge_mlp3(
    const __bf16* __restrict__ Yb,    // [NN][128]
    const __bf16* __restrict__ eabs,  // [NE][32] sorted
    const int* __restrict__ srcp, const int* __restrict__ dstp,
    const __bf16* __restrict__ w1t,   // [128][DIN]; e-part at col offset F
    const float* __restrict__ b1,
    const __bf16* __restrict__ w2t,   // [128][128]
    const float* __restrict__ b2,
    float* __restrict__ agg,          // [NN][128] fp32
    int ntiles)
{
  constexpr int F = DIN - 32;
  __shared__ __bf16 Mid[128][136];
  __shared__ __bf16 Ae[128][40];
  __shared__ int dst_s[128];

  const int tid   = threadIdx.x;
  const int lane  = tid & 63;
  const int w     = tid >> 6;
  const int colq  = lane & 15;
  const int krow  = (lane >> 4) * 8;
  const int rbase = (lane >> 4) * 4;
  const int col   = w * 16 + colq;

  // ---- per-block constants: B fragments + biases ----
  bf16x8 b1f = *reinterpret_cast<const bf16x8*>(w1t + (size_t)col * DIN + F + krow);
  bf16x8 b2f[4];
#pragma unroll
  for (int ks = 0; ks < 4; ++ks)
    b2f[ks] = *reinterpret_cast<const bf16x8*>(w2t + (size_t)col * H + ks * 32 + krow);
  const float b1s = b1[col];
  const float b2s = b2[col];

  // staging thread mapping
  const int yrow = tid >> 4;    // 0..31 (+32k)
  const int yc   = tid & 15;
  const int erow = tid >> 2;    // 0..127
  const int ec   = tid & 3;
  const int drow = tid & 127;

  int t0 = blockIdx.x * 4;
  int t1 = t0 + 4; if (t1 > ntiles) t1 = ntiles;
  if (t0 >= ntiles) return;

  // ---- prologue: stage tile t0 into regs; prefetch src(t0+1) ----
  int e0 = t0 * 128;
  int sA[4];
#pragma unroll
  for (int k = 0; k < 4; ++k) sA[k] = srcp[e0 + yrow + 32 * k];
  int dreg = dstp[e0 + drow];
  bf16x8 eareg = *reinterpret_cast<const bf16x8*>(eabs + (size_t)(e0 + erow) * FE + ec * 8);
  bf16x8 yreg[4];
#pragma unroll
  for (int k = 0; k < 4; ++k)
    yreg[k] = *reinterpret_cast<const bf16x8*>(Yb + (size_t)sA[k] * H + yc * 8);
  {
    int e0n = (t0 + 1 < t1) ? (t0 + 1) * 128 : e0;
#pragma unroll
    for (int k = 0; k < 4; ++k) sA[k] = srcp[e0n + yrow + 32 * k];
  }

  for (int t = t0; t < t1; ++t) {
    __syncthreads();                       // B0: Mid/Ae/dst free (prev reduce done)
    // ---- WRITE staged regs -> LDS ----
#pragma unroll
    for (int k = 0; k < 4; ++k)
      *reinterpret_cast<bf16x8*>(&Mid[yrow + 32 * k][yc * 8]) = yreg[k];
    *reinterpret_cast<bf16x8*>(&Ae[erow][ec * 8]) = eareg;
    if (tid < 128) dst_s[tid] = dreg;
    __syncthreads();                       // B1: stage visible

    // ---- ISSUE tile t+1 gathers (overlap with compute below) ----
    if (t + 1 < t1) {
      int e1 = (t + 1) * 128;
#pragma unroll
      for (int k = 0; k < 4; ++k)
        yreg[k] = *reinterpret_cast<const bf16x8*>(Yb + (size_t)sA[k] * H + yc * 8);
      eareg = *reinterpret_cast<const bf16x8*>(eabs + (size_t)(e1 + erow) * FE + ec * 8);
      dreg = dstp[e1 + drow];
      int e2 = (t + 2 < t1) ? (t + 2) * 128 : e1;
#pragma unroll
      for (int k = 0; k < 4; ++k) sA[k] = srcp[e2 + yrow + 32 * k];
    }

    // ---- GEMM1e: ea @ W1e + b1 ----
    f32x4 acc[8];
#pragma unroll
    for (int mt = 0; mt < 8; ++mt) acc[mt] = (f32x4){b1s, b1s, b1s, b1s};
#pragma unroll
    for (int mt = 0; mt < 8; ++mt) {
      bf16x8 a = *reinterpret_cast<const bf16x8*>(&Ae[mt * 16 + colq][krow]);
      acc[mt] = __builtin_amdgcn_mfma_f32_16x16x32_bf16(a, b1f, acc[mt], 0, 0, 0);
    }

    // ---- RMW: Mid = relu(Y + acc) ----
#pragma unroll
    for (int mt = 0; mt < 8; ++mt)
#pragma unroll
      for (int r = 0; r < 4; ++r) {
        int row = mt * 16 + rbase + r;
        float v = (float)Mid[row][col] + acc[mt][r];
        Mid[row][col] = (__bf16)fmaxf(v, 0.f);
      }
    __syncthreads();                       // B2: Mid complete

    // ---- GEMM2: Mid @ W2 + b2 ----
    f32x4 acc2[8];
#pragma unroll
    for (int mt = 0; mt < 8; ++mt) acc2[mt] = (f32x4){b2s, b2s, b2s, b2s};
#pragma unroll
    for (int ks = 0; ks < 4; ++ks)
#pragma unroll
      for (int mt = 0; mt < 8; ++mt) {
        bf16x8 a = *reinterpret_cast<const bf16x8*>(&Mid[mt * 16 + colq][ks * 32 + krow]);
        acc2[mt] = __builtin_amdgcn_mfma_f32_16x16x32_bf16(a, b2f[ks], acc2[mt], 0, 0, 0);
      }
    __syncthreads();                       // B3: Mid fully consumed

    // ---- Out overlay (bf16 into Mid) ----
#pragma unroll
    for (int mt = 0; mt < 8; ++mt)
#pragma unroll
      for (int r = 0; r < 4; ++r)
        Mid[mt * 16 + rbase + r][col] = (__bf16)acc2[mt][r];
    __syncthreads();                       // B4: Out visible

    // ---- segment reduce over sorted dst ----
    {
      const int rc = tid & 127;
      const int q  = tid >> 7;
      const int r0 = q * 32;
      float s = (float)Mid[r0][rc];
      int d = dst_s[r0];
      for (int r = r0 + 1; r < r0 + 32; ++r) {
        int dn = dst_s[r];
        if (dn != d) {
          atomicAdd(agg + (size_t)d * H + rc, s);
          s = 0.f;
          d = dn;
        }
        s += (float)Mid[r][rc];
      }
      atomicAdd(agg + (size_t)d * H + rc, s);
    }
  }
}

// ---------------- pooling ----------------
__global__ void pool_kernel(const float* __restrict__ agg, const int* __restrict__ batch,
                            float* __restrict__ sums, float* __restrict__ cnts) {
  const int col = threadIdx.x & 127;
  const int sub = threadIdx.x >> 7;
  const int NB = 128;
  int n0 = blockIdx.x * NB + sub * (NB / 2);
  if (n0 >= NN) return;
  int n1 = n0 + NB / 2; if (n1 > NN) n1 = NN;
  float s = 0.f, c = 0.f;
  int g = batch[n0];
  for (int n = n0; n < n1; ++n) {
    int gn = batch[n];
    if (gn != g) {
      atomicAdd(&sums[g * H + col], s);
      if (col == 0) atomicAdd(&cnts[g], c);
      s = 0.f; c = 0.f; g = gn;
    }
    s += fmaxf(agg[(size_t)n * H + col], 0.f);
    c += 1.f;
  }
  atomicAdd(&sums[g * H + col], s);
  if (col == 0) atomicAdd(&cnts[g], c);
}

__global__ void final_kernel(const float* __restrict__ sums, const float* __restrict__ cnts,
                             const float* __restrict__ lw, const float* __restrict__ lb,
                             float* __restrict__ out) {
  int idx = blockIdx.x * blockDim.x + threadIdx.x;
  if (idx >= NG * OD) return;
  int g = idx / OD, o = idx % OD;
  float inv = 1.f / fmaxf(cnts[g], 1.f);
  float s = 0.f;
#pragma unroll 8
  for (int k = 0; k < H; ++k)
    s += sums[g * H + k] * lw[k * OD + o];
  out[idx] = s * inv + lb[o];
}

// ---------------- launcher ----------------
extern "C" void kernel_launch(void* const* d_in, const int* in_sizes, int n_in,
                              void* d_out, int out_size, void* d_ws, size_t ws_size,
                              hipStream_t stream) {
  const float* x   = (const float*)d_in[0];
  const int*   ei  = (const int*)d_in[1];
  const float* ea  = (const float*)d_in[2];
  const int*   bat = (const int*)d_in[3];
  const float* w1[3] = {(const float*)d_in[4], (const float*)d_in[8],  (const float*)d_in[12]};
  const float* b1[3] = {(const float*)d_in[5], (const float*)d_in[9],  (const float*)d_in[13]};
  const float* w2[3] = {(const float*)d_in[6], (const float*)d_in[10], (const float*)d_in[14]};
  const float* b2[3] = {(const float*)d_in[7], (const float*)d_in[11], (const float*)d_in[15]};
  const float* lw  = (const float*)d_in[16];
  const float* lb  = (const float*)d_in[17];
  float* out = (float*)d_out;

  char* ws = (char*)d_ws;
  size_t off = 0;
  auto alloc = [&](size_t bytes) -> void* {
    void* p = ws + off;
    off = (off + bytes + 255) & ~(size_t)255;
    return p;
  };
  __bf16* xb   = (__bf16*)alloc((size_t)NN * FX * 2);
  __bf16* Yb   = (__bf16*)alloc((size_t)NN * H * 2);
  __bf16* eabs = (__bf16*)alloc((size_t)NE * FE * 2);
  float*  agg  = (float*) alloc((size_t)NN * H * 4);
  __bf16* w1t[3]; __bf16* w2t[3];
  for (int l = 0; l < 3; ++l) {
    w1t[l] = (__bf16*)alloc(128 * 160 * 2);
    w2t[l] = (__bf16*)alloc(128 * 128 * 2);
  }
  float* sums = (float*)alloc(NG * H * 4);
  float* cnts = (float*)alloc(NG * 4);
  int* hist   = (int*)alloc((size_t)NN * 4);
  int* excl   = (int*)alloc((size_t)NN * 4);
  int* btot   = (int*)alloc(256 * 4);
  int* cursor = (int*)alloc((size_t)NN * 4);
  int* srcp   = (int*)alloc((size_t)NE * 4);
  int* dstp   = (int*)alloc((size_t)NE * 4);
  int* eperm  = (int*)alloc((size_t)NE * 4);

  const int* src = ei;
  const int* dst = ei + NE;
  const int NB_SCAN = (NN + 255) / 256;
  const int NTILES = NE / 128;             // 6250
  const int EGRID  = (NTILES + 3) / 4;     // 1563

  // conversions
  cvt_f32_bf16<<<(NN * FX / 4 + 255) / 256, 256, 0, stream>>>(x, xb, NN * FX);
  const int dins[3] = {96, 160, 160};
  for (int l = 0; l < 3; ++l) {
    cvt_w_t<<<(dins[l] * 128 + 255) / 256, 256, 0, stream>>>(w1[l], w1t[l], dins[l]);
    cvt_w_t<<<(128 * 128 + 255) / 256, 256, 0, stream>>>(w2[l], w2t[l], 128);
  }

  // counting sort by dst + sorted bf16 edge_attr
  hipMemsetAsync(hist, 0, (size_t)NN * 4, stream);
  hist_build<<<(NE + 255) / 256, 256, 0, stream>>>(dst, hist);
  scan1<<<NB_SCAN, 256, 0, stream>>>(hist, excl, btot);
  scan2<<<1, 256, 0, stream>>>(btot, NB_SCAN);
  scan3<<<NB_SCAN, 256, 0, stream>>>(excl, btot, cursor);
  scatter_perm<<<(NE + 255) / 256, 256, 0, stream>>>(src, dst, cursor, srcp, dstp, eperm);
  sort_ea<<<(NE * 4 + 255) / 256, 256, 0, stream>>>(ea, eperm, eabs);

  // layers
  const int NGRID = (NN + 127) / 128;      // 391
  for (int l = 0; l < 3; ++l) {
    if (l == 0)
      node_gemm2<64, 96, false><<<NGRID, 512, 0, stream>>>(xb, w1t[0], Yb);
    else
      node_gemm2<128, 160, true><<<NGRID, 512, 0, stream>>>(agg, w1t[l], Yb);

    hipMemsetAsync(agg, 0, (size_t)NN * H * 4, stream);
    if (l == 0)
      edge_mlp3<96><<<EGRID, 512, 0, stream>>>(Yb, eabs, srcp, dstp,
                                               w1t[0], b1[0], w2t[0], b2[0], agg, NTILES);
    else
      edge_mlp3<160><<<EGRID, 512, 0, stream>>>(Yb, eabs, srcp, dstp,
                                                w1t[l], b1[l], w2t[l], b2[l], agg, NTILES);
  }

  hipMemsetAsync(sums, 0, NG * H * 4, stream);
  hipMemsetAsync(cnts, 0, NG * 4, stream);
  pool_kernel<<<(NN + 127) / 128, 256, 0, stream>>>(agg, bat, sums, cnts);
  final_kernel<<<(NG * OD + 255) / 256, 256, 0, stream>>>(sums, cnts, lw, lb, out);
}

// Round 5
// 481.416 us; speedup vs baseline: 2.3885x; 1.1667x over previous
//
#include <hip/hip_runtime.h>
#include <hip/hip_bf16.h>
#include <stdint.h>

typedef __attribute__((ext_vector_type(8))) __bf16 bf16x8;
typedef __attribute__((ext_vector_type(4))) __bf16 bf16x4;
typedef __attribute__((ext_vector_type(4))) float f32x4;

static constexpr int NN = 50000;
static constexpr int NE = 800000;
static constexpr int FX = 64;
static constexpr int FE = 32;
static constexpr int H  = 128;
static constexpr int NG = 128;
static constexpr int OD = 8;

// ---------------- conversion kernels ----------------
__global__ void cvt_f32_bf16(const float* __restrict__ in, __bf16* __restrict__ out, int n) {
  int idx = (blockIdx.x * blockDim.x + threadIdx.x) * 4;
  if (idx + 3 < n) {
    float4 v = *reinterpret_cast<const float4*>(in + idx);
    bf16x4 o;
    o[0] = (__bf16)v.x; o[1] = (__bf16)v.y; o[2] = (__bf16)v.z; o[3] = (__bf16)v.w;
    *reinterpret_cast<bf16x4*>(out + idx) = o;
  } else {
    for (; idx < n; ++idx) out[idx] = (__bf16)in[idx];
  }
}

// w: [K][128] f32 -> wt: [128][K] bf16
__global__ void cvt_w_t(const float* __restrict__ w, __bf16* __restrict__ wt, int K) {
  int i = blockIdx.x * blockDim.x + threadIdx.x;
  if (i >= K * 128) return;
  int n = i / K, k = i % K;
  wt[i] = (__bf16)w[k * 128 + n];
}

// ---------------- counting sort of edges by dst ----------------
__global__ void hist_build(const int* __restrict__ dst, int* __restrict__ hist) {
  int e = blockIdx.x * blockDim.x + threadIdx.x;
  if (e < NE) atomicAdd(&hist[dst[e]], 1);
}

__global__ void scan1(const int* __restrict__ hist, int* __restrict__ excl, int* __restrict__ btot) {
  __shared__ int tmp[256];
  int t = threadIdx.x;
  int i = blockIdx.x * 256 + t;
  int v = (i < NN) ? hist[i] : 0;
  tmp[t] = v;
  __syncthreads();
  for (int off = 1; off < 256; off <<= 1) {
    int add = (t >= off) ? tmp[t - off] : 0;
    __syncthreads();
    tmp[t] += add;
    __syncthreads();
  }
  if (i < NN) excl[i] = tmp[t] - v;
  if (t == 255) btot[blockIdx.x] = tmp[255];
}

__global__ void scan2(int* __restrict__ btot, int nb) {
  __shared__ int tmp[256];
  int t = threadIdx.x;
  int v = (t < nb) ? btot[t] : 0;
  tmp[t] = v;
  __syncthreads();
  for (int off = 1; off < 256; off <<= 1) {
    int add = (t >= off) ? tmp[t - off] : 0;
    __syncthreads();
    tmp[t] += add;
    __syncthreads();
  }
  if (t < nb) btot[t] = tmp[t] - v;
}

__global__ void scan3(const int* __restrict__ excl, const int* __restrict__ btot,
                      int* __restrict__ cursor) {
  int i = blockIdx.x * 256 + threadIdx.x;
  if (i < NN) cursor[i] = excl[i] + btot[blockIdx.x];
}

__global__ void scatter_perm(const int* __restrict__ src, const int* __restrict__ dst,
                             int* __restrict__ cursor,
                             int* __restrict__ srcp, int* __restrict__ dstp,
                             int* __restrict__ eperm) {
  int e = blockIdx.x * blockDim.x + threadIdx.x;
  if (e >= NE) return;
  int d = dst[e];
  int p = atomicAdd(&cursor[d], 1);
  srcp[p] = src[e];
  dstp[p] = d;
  eperm[p] = e;
}

// edge_attr -> bf16, permuted to sorted order (one-time)
__global__ void sort_ea(const float* __restrict__ ea, const int* __restrict__ eperm,
                        __bf16* __restrict__ eabs) {
  int i = blockIdx.x * blockDim.x + threadIdx.x;
  if (i >= NE * 4) return;
  int p = i >> 2, c = i & 3;
  int e = eperm[p];
  float4 v0 = *reinterpret_cast<const float4*>(ea + (size_t)e * FE + c * 8);
  float4 v1 = *reinterpret_cast<const float4*>(ea + (size_t)e * FE + c * 8 + 4);
  bf16x8 o;
  o[0] = (__bf16)v0.x; o[1] = (__bf16)v0.y; o[2] = (__bf16)v0.z; o[3] = (__bf16)v0.w;
  o[4] = (__bf16)v1.x; o[5] = (__bf16)v1.y; o[6] = (__bf16)v1.z; o[7] = (__bf16)v1.w;
  *reinterpret_cast<bf16x8*>(eabs + (size_t)p * FE + c * 8) = o;
}

// ---------------- layer-0 node GEMM: Y = x @ W1h ----------------
template<int F, int DIN>
__global__ __launch_bounds__(512) void node_gemm2(
    const __bf16* __restrict__ Ain,
    const __bf16* __restrict__ wt,   // [128][DIN], h-part at col offset 0
    __bf16* __restrict__ Y)          // [NN][128]
{
  constexpr int APAD = F + 8;
  constexpr int KS   = F / 32;
  constexpr int CH   = F / 8;
  constexpr int AB   = 128 * APAD * 2;
  constexpr int OB   = 128 * 136 * 2;
  constexpr int SB   = (AB > OB) ? AB : OB;
  __shared__ __align__(16) char smem[SB];
  auto As  = reinterpret_cast<__bf16 (*)[APAD]>(smem);
  auto Ost = reinterpret_cast<__bf16 (*)[136]>(smem);

  const int tid   = threadIdx.x;
  const int lane  = tid & 63;
  const int w     = tid >> 6;
  const int m0    = blockIdx.x * 128;
  const int colq  = lane & 15;
  const int krow  = (lane >> 4) * 8;
  const int rbase = (lane >> 4) * 4;
  const int col   = w * 16 + colq;

  bf16x8 bf[KS];
#pragma unroll
  for (int ks = 0; ks < KS; ++ks)
    bf[ks] = *reinterpret_cast<const bf16x8*>(wt + (size_t)col * DIN + ks * 32 + krow);

  for (int i = tid; i < 128 * CH; i += 512) {
    int row = i / CH, c = i % CH;
    int g = m0 + row; if (g >= NN) g = NN - 1;
    *reinterpret_cast<bf16x8*>(&As[row][c * 8]) =
        *reinterpret_cast<const bf16x8*>(Ain + (size_t)g * F + c * 8);
  }
  __syncthreads();

  f32x4 acc[8];
#pragma unroll
  for (int mt = 0; mt < 8; ++mt) acc[mt] = (f32x4){0.f, 0.f, 0.f, 0.f};
#pragma unroll
  for (int ks = 0; ks < KS; ++ks)
#pragma unroll
    for (int mt = 0; mt < 8; ++mt) {
      bf16x8 a = *reinterpret_cast<const bf16x8*>(&As[mt * 16 + colq][ks * 32 + krow]);
      acc[mt] = __builtin_amdgcn_mfma_f32_16x16x32_bf16(a, bf[ks], acc[mt], 0, 0, 0);
    }
  __syncthreads();   // done reading As; Ost aliases it

#pragma unroll
  for (int mt = 0; mt < 8; ++mt)
#pragma unroll
    for (int r = 0; r < 4; ++r)
      Ost[mt * 16 + rbase + r][col] = (__bf16)acc[mt][r];
  __syncthreads();

  for (int i = tid; i < 128 * 16; i += 512) {
    int row = i >> 4, c = i & 15;
    int g = m0 + row;
    if (g < NN)
      *reinterpret_cast<bf16x8*>(Y + (size_t)g * H + c * 8) =
          *reinterpret_cast<const bf16x8*>(&Ost[row][c * 8]);
  }
}

// ---------------- node kernel: h = relu(aggH@W2 + deg*b2); [Y = h@W1h] ----------------
// WRITE_Y: chain into next layer's Y. !WRITE_Y: write pre-relu f32 (pool applies relu).
template<bool WRITE_Y>
__global__ __launch_bounds__(512) void node_wy(
    const float* __restrict__ aggHin,  // [NN][128] f32
    const int* __restrict__ deg,       // hist (edges per dst)
    const __bf16* __restrict__ w2t,    // [128][128]
    const float* __restrict__ b2,
    const __bf16* __restrict__ w1t,    // [128][160], h-part at 0 (WRITE_Y only)
    __bf16* __restrict__ Y,            // WRITE_Y only
    float* __restrict__ hpre)          // !WRITE_Y only (may alias aggHin)
{
  __shared__ __bf16 Ast[128][136];
  __shared__ __bf16 Hst[WRITE_Y ? 128 : 1][136];
  __shared__ int deg_s[128];

  const int tid   = threadIdx.x;
  const int lane  = tid & 63;
  const int w     = tid >> 6;
  const int m0    = blockIdx.x * 128;
  const int colq  = lane & 15;
  const int krow  = (lane >> 4) * 8;
  const int rbase = (lane >> 4) * 4;
  const int col   = w * 16 + colq;

  // stage aggH (f32 -> bf16)
  for (int i = tid; i < 128 * 16; i += 512) {
    int row = i >> 4, cb = (i & 15) * 8;
    int g = m0 + row; if (g >= NN) g = NN - 1;
    const float* s = aggHin + (size_t)g * H + cb;
    float4 v0 = *reinterpret_cast<const float4*>(s);
    float4 v1 = *reinterpret_cast<const float4*>(s + 4);
    bf16x8 o;
    o[0] = (__bf16)v0.x; o[1] = (__bf16)v0.y; o[2] = (__bf16)v0.z; o[3] = (__bf16)v0.w;
    o[4] = (__bf16)v1.x; o[5] = (__bf16)v1.y; o[6] = (__bf16)v1.z; o[7] = (__bf16)v1.w;
    *reinterpret_cast<bf16x8*>(&Ast[row][cb]) = o;
  }
  if (tid < 128) {
    int g = m0 + tid;
    deg_s[tid] = (g < NN) ? deg[g] : 0;
  }
  __syncthreads();

  bf16x8 w2f[4];
#pragma unroll
  for (int ks = 0; ks < 4; ++ks)
    w2f[ks] = *reinterpret_cast<const bf16x8*>(w2t + (size_t)col * H + ks * 32 + krow);
  const float b2s = b2[col];

  f32x4 acc[8];
#pragma unroll
  for (int mt = 0; mt < 8; ++mt) acc[mt] = (f32x4){0.f, 0.f, 0.f, 0.f};
#pragma unroll
  for (int ks = 0; ks < 4; ++ks)
#pragma unroll
    for (int mt = 0; mt < 8; ++mt) {
      bf16x8 a = *reinterpret_cast<const bf16x8*>(&Ast[mt * 16 + colq][ks * 32 + krow]);
      acc[mt] = __builtin_amdgcn_mfma_f32_16x16x32_bf16(a, w2f[ks], acc[mt], 0, 0, 0);
    }

  if (WRITE_Y) {
#pragma unroll
    for (int mt = 0; mt < 8; ++mt)
#pragma unroll
      for (int r = 0; r < 4; ++r) {
        int row = mt * 16 + rbase + r;
        float v = acc[mt][r] + (float)deg_s[row] * b2s;
        Hst[row][col] = (__bf16)fmaxf(v, 0.f);
      }
    __syncthreads();   // Hst complete; Ast dead

    bf16x8 w1f[4];
#pragma unroll
    for (int ks = 0; ks < 4; ++ks)
      w1f[ks] = *reinterpret_cast<const bf16x8*>(w1t + (size_t)col * 160 + ks * 32 + krow);

    f32x4 acc2[8];
#pragma unroll
    for (int mt = 0; mt < 8; ++mt) acc2[mt] = (f32x4){0.f, 0.f, 0.f, 0.f};
#pragma unroll
    for (int ks = 0; ks < 4; ++ks)
#pragma unroll
      for (int mt = 0; mt < 8; ++mt) {
        bf16x8 a = *reinterpret_cast<const bf16x8*>(&Hst[mt * 16 + colq][ks * 32 + krow]);
        acc2[mt] = __builtin_amdgcn_mfma_f32_16x16x32_bf16(a, w1f[ks], acc2[mt], 0, 0, 0);
      }

    // Ost overlays Ast
#pragma unroll
    for (int mt = 0; mt < 8; ++mt)
#pragma unroll
      for (int r = 0; r < 4; ++r)
        Ast[mt * 16 + rbase + r][col] = (__bf16)acc2[mt][r];
    __syncthreads();

    for (int i = tid; i < 128 * 16; i += 512) {
      int row = i >> 4, cb = (i & 15) * 8;
      int g = m0 + row;
      if (g < NN)
        *reinterpret_cast<bf16x8*>(Y + (size_t)g * H + cb) =
            *reinterpret_cast<const bf16x8*>(&Ast[row][cb]);
    }
  } else {
#pragma unroll
    for (int mt = 0; mt < 8; ++mt)
#pragma unroll
      for (int r = 0; r < 4; ++r) {
        int row = mt * 16 + rbase + r;
        int g = m0 + row;
        if (g < NN)
          hpre[(size_t)g * H + col] = acc[mt][r] + (float)deg_s[row] * b2s;
      }
  }
}

// ---------------- edge kernel: aggH[dst] += relu(Y[src] + ea@W1e + b1) ----------------
// 128 dst-sorted edges/tile, TPB tiles per block, 512 threads = 8 waves x 16 cols.
// Y tile in LDS is rot-swizzled: physical col = (col + ((row>>2)&3)*16) & 127
// -> C-layout scalar access hits 4 disjoint 8-bank groups (conflict-free).
template<int DIN>
__global__ __launch_bounds__(512) void edge_mlp4(
    const __bf16* __restrict__ Yb,    // [NN][128]
    const __bf16* __restrict__ eabs,  // [NE][32] sorted
    const int* __restrict__ srcp, const int* __restrict__ dstp,
    const __bf16* __restrict__ w1t,   // [128][DIN]; e-part at col offset F
    const float* __restrict__ b1,
    float* __restrict__ aggH,         // [NN][128] f32
    int ntiles)
{
  constexpr int F = DIN - 32;
  constexpr int TPB = 4;
  __shared__ __bf16 Ylds[128][128];
  __shared__ int dst_s[128];

  const int tid   = threadIdx.x;
  const int lane  = tid & 63;
  const int w     = tid >> 6;
  const int colq  = lane & 15;
  const int krow  = (lane >> 4) * 8;
  const int rbase = (lane >> 4) * 4;
  const int col   = w * 16 + colq;

  const bf16x8 b1f = *reinterpret_cast<const bf16x8*>(w1t + (size_t)col * DIN + F + krow);
  const float  b1s = b1[col];

  const int yrow = tid >> 4;    // 0..31
  const int yc   = tid & 15;
  const int drow = tid & 127;

  int t0 = blockIdx.x * TPB;
  int t1 = t0 + TPB; if (t1 > ntiles) t1 = ntiles;
  if (t0 >= ntiles) return;

  // ---- prologue: tile t0 data; t0+1 src indices ----
  int e0 = t0 * 128;
  int sA[4];
#pragma unroll
  for (int k = 0; k < 4; ++k) sA[k] = srcp[e0 + yrow + 32 * k];
  int dreg = dstp[e0 + drow];
  bf16x8 yreg[4];
#pragma unroll
  for (int k = 0; k < 4; ++k)
    yreg[k] = *reinterpret_cast<const bf16x8*>(Yb + (size_t)sA[k] * H + yc * 8);
  bf16x8 aef[8];
#pragma unroll
  for (int mt = 0; mt < 8; ++mt)
    aef[mt] = *reinterpret_cast<const bf16x8*>(eabs + (size_t)(e0 + mt * 16 + colq) * FE + krow);
  {
    int e0n = (t0 + 1 < t1) ? (t0 + 1) * 128 : e0;
#pragma unroll
    for (int k = 0; k < 4; ++k) sA[k] = srcp[e0n + yrow + 32 * k];
  }

  for (int t = t0; t < t1; ++t) {
    __syncthreads();                     // Ylds free (prev reduce done)
    // stage Y regs -> LDS (rot-swizzled chunks)
#pragma unroll
    for (int k = 0; k < 4; ++k) {
      int row = yrow + 32 * k;
      int cb = (yc * 8 + ((row >> 2) & 3) * 16) & 127;
      *reinterpret_cast<bf16x8*>(&Ylds[row][cb]) = yreg[k];
    }
    if (tid < 128) dst_s[tid] = dreg;
    __syncthreads();                     // stage visible

    // issue next-tile Y/dst gathers (hide under compute)
    if (t + 1 < t1) {
      int e1 = (t + 1) * 128;
#pragma unroll
      for (int k = 0; k < 4; ++k)
        yreg[k] = *reinterpret_cast<const bf16x8*>(Yb + (size_t)sA[k] * H + yc * 8);
      dreg = dstp[e1 + drow];
      int e2 = (t + 2 < t1) ? (t + 2) * 128 : e1;
#pragma unroll
      for (int k = 0; k < 4; ++k) sA[k] = srcp[e2 + yrow + 32 * k];
    }

    // GEMM1e: ea @ W1e + b1 (K=32, one step)
    f32x4 acc[8];
#pragma unroll
    for (int mt = 0; mt < 8; ++mt) acc[mt] = (f32x4){b1s, b1s, b1s, b1s};
#pragma unroll
    for (int mt = 0; mt < 8; ++mt)
      acc[mt] = __builtin_amdgcn_mfma_f32_16x16x32_bf16(aef[mt], b1f, acc[mt], 0, 0, 0);

    // prefetch next-tile ea fragments (aef now dead)
    if (t + 1 < t1) {
      int e1 = (t + 1) * 128;
#pragma unroll
      for (int mt = 0; mt < 8; ++mt)
        aef[mt] = *reinterpret_cast<const bf16x8*>(eabs + (size_t)(e1 + mt * 16 + colq) * FE + krow);
    }

    // in-place: Ylds = relu(Y + ea@W1e + b1)   (each element owned by one thread)
#pragma unroll
    for (int mt = 0; mt < 8; ++mt)
#pragma unroll
      for (int r = 0; r < 4; ++r) {
        int row = mt * 16 + rbase + r;
        int cs = (col + ((row >> 2) & 3) * 16) & 127;
        float v = (float)Ylds[row][cs] + acc[mt][r];
        Ylds[row][cs] = (__bf16)fmaxf(v, 0.f);
      }
    __syncthreads();                     // Mid complete

    // segment reduce over sorted dst: 4 threads/col, 32 rows each
    {
      const int rc = tid & 127;
      const int r0 = (tid >> 7) * 32;
      float s = 0.f;
      int d = dst_s[r0];
#pragma unroll 4
      for (int r = r0; r < r0 + 32; ++r) {
        int dn = dst_s[r];
        float v = (float)Ylds[r][(rc + ((r >> 2) & 3) * 16) & 127];
        if (dn != d) { atomicAdd(aggH + (size_t)d * H + rc, s); s = 0.f; d = dn; }
        s += v;
      }
      atomicAdd(aggH + (size_t)d * H + rc, s);
    }
  }
}

// ---------------- pooling ----------------
__global__ void pool_kernel(const float* __restrict__ agg, const int* __restrict__ batch,
                            float* __restrict__ sums, float* __restrict__ cnts) {
  const int col = threadIdx.x & 127;
  const int sub = threadIdx.x >> 7;
  const int NB = 128;
  int n0 = blockIdx.x * NB + sub * (NB / 2);
  if (n0 >= NN) return;
  int n1 = n0 + NB / 2; if (n1 > NN) n1 = NN;
  float s = 0.f, c = 0.f;
  int g = batch[n0];
  for (int n = n0; n < n1; ++n) {
    int gn = batch[n];
    if (gn != g) {
      atomicAdd(&sums[g * H + col], s);
      if (col == 0) atomicAdd(&cnts[g], c);
      s = 0.f; c = 0.f; g = gn;
    }
    s += fmaxf(agg[(size_t)n * H + col], 0.f);   // relu of final layer fused here
    c += 1.f;
  }
  atomicAdd(&sums[g * H + col], s);
  if (col == 0) atomicAdd(&cnts[g], c);
}

__global__ void final_kernel(const float* __restrict__ sums, const float* __restrict__ cnts,
                             const float* __restrict__ lw, const float* __restrict__ lb,
                             float* __restrict__ out) {
  int idx = blockIdx.x * blockDim.x + threadIdx.x;
  if (idx >= NG * OD) return;
  int g = idx / OD, o = idx % OD;
  float inv = 1.f / fmaxf(cnts[g], 1.f);
  float s = 0.f;
#pragma unroll 8
  for (int k = 0; k < H; ++k)
    s += sums[g * H + k] * lw[k * OD + o];
  out[idx] = s * inv + lb[o];
}

// ---------------- launcher ----------------
extern "C" void kernel_launch(void* const* d_in, const int* in_sizes, int n_in,
                              void* d_out, int out_size, void* d_ws, size_t ws_size,
                              hipStream_t stream) {
  const float* x   = (const float*)d_in[0];
  const int*   ei  = (const int*)d_in[1];
  const float* ea  = (const float*)d_in[2];
  const int*   bat = (const int*)d_in[3];
  const float* w1[3] = {(const float*)d_in[4], (const float*)d_in[8],  (const float*)d_in[12]};
  const float* b1[3] = {(const float*)d_in[5], (const float*)d_in[9],  (const float*)d_in[13]};
  const float* w2[3] = {(const float*)d_in[6], (const float*)d_in[10], (const float*)d_in[14]};
  const float* b2[3] = {(const float*)d_in[7], (const float*)d_in[11], (const float*)d_in[15]};
  const float* lw  = (const float*)d_in[16];
  const float* lb  = (const float*)d_in[17];
  float* out = (float*)d_out;

  char* ws = (char*)d_ws;
  size_t off = 0;
  auto alloc = [&](size_t bytes) -> void* {
    void* p = ws + off;
    off = (off + bytes + 255) & ~(size_t)255;
    return p;
  };
  __bf16* xb   = (__bf16*)alloc((size_t)NN * FX * 2);
  __bf16* Yb   = (__bf16*)alloc((size_t)NN * H * 2);
  __bf16* eabs = (__bf16*)alloc((size_t)NE * FE * 2);
  float*  agg  = (float*) alloc((size_t)NN * H * 4);
  __bf16* w1t[3]; __bf16* w2t[3];
  for (int l = 0; l < 3; ++l) {
    w1t[l] = (__bf16*)alloc(128 * 160 * 2);
    w2t[l] = (__bf16*)alloc(128 * 128 * 2);
  }
  float* sums = (float*)alloc(NG * H * 4);
  float* cnts = (float*)alloc(NG * 4);
  int* hist   = (int*)alloc((size_t)NN * 4);
  int* excl   = (int*)alloc((size_t)NN * 4);
  int* btot   = (int*)alloc(256 * 4);
  int* cursor = (int*)alloc((size_t)NN * 4);
  int* srcp   = (int*)alloc((size_t)NE * 4);
  int* dstp   = (int*)alloc((size_t)NE * 4);
  int* eperm  = (int*)alloc((size_t)NE * 4);

  const int* src = ei;
  const int* dst = ei + NE;
  const int NB_SCAN = (NN + 255) / 256;
  const int NTILES = NE / 128;             // 6250
  const int EGRID  = (NTILES + 3) / 4;     // 1563
  const int NGRID  = (NN + 127) / 128;     // 391

  // conversions
  cvt_f32_bf16<<<(NN * FX / 4 + 255) / 256, 256, 0, stream>>>(x, xb, NN * FX);
  const int dins[3] = {96, 160, 160};
  for (int l = 0; l < 3; ++l) {
    cvt_w_t<<<(dins[l] * 128 + 255) / 256, 256, 0, stream>>>(w1[l], w1t[l], dins[l]);
    cvt_w_t<<<(128 * 128 + 255) / 256, 256, 0, stream>>>(w2[l], w2t[l], 128);
  }

  // counting sort by dst (hist doubles as deg) + sorted bf16 edge_attr
  hipMemsetAsync(hist, 0, (size_t)NN * 4, stream);
  hist_build<<<(NE + 255) / 256, 256, 0, stream>>>(dst, hist);
  scan1<<<NB_SCAN, 256, 0, stream>>>(hist, excl, btot);
  scan2<<<1, 256, 0, stream>>>(btot, NB_SCAN);
  scan3<<<NB_SCAN, 256, 0, stream>>>(excl, btot, cursor);
  scatter_perm<<<(NE + 255) / 256, 256, 0, stream>>>(src, dst, cursor, srcp, dstp, eperm);
  sort_ea<<<(NE * 4 + 255) / 256, 256, 0, stream>>>(ea, eperm, eabs);

  // ---- layer 0 ----
  node_gemm2<64, 96><<<NGRID, 512, 0, stream>>>(xb, w1t[0], Yb);
  hipMemsetAsync(agg, 0, (size_t)NN * H * 4, stream);
  edge_mlp4<96><<<EGRID, 512, 0, stream>>>(Yb, eabs, srcp, dstp, w1t[0], b1[0], agg, NTILES);

  // ---- layers 1,2 ----
  for (int l = 1; l < 3; ++l) {
    node_wy<true><<<NGRID, 512, 0, stream>>>(agg, hist, w2t[l - 1], b2[l - 1],
                                             w1t[l], Yb, nullptr);
    hipMemsetAsync(agg, 0, (size_t)NN * H * 4, stream);
    edge_mlp4<160><<<EGRID, 512, 0, stream>>>(Yb, eabs, srcp, dstp, w1t[l], b1[l], agg, NTILES);
  }

  // ---- final W2 stage (pre-relu, in-place) + pool + head ----
  node_wy<false><<<NGRID, 512, 0, stream>>>(agg, hist, w2t[2], b2[2],
                                            nullptr, nullptr, agg);
  hipMemsetAsync(sums, 0, NG * H * 4, stream);
  hipMemsetAsync(cnts, 0, NG * 4, stream);
  pool_kernel<<<(NN + 127) / 128, 256, 0, stream>>>(agg, bat, sums, cnts);
  final_kernel<<<(NG * OD + 255) / 256, 256, 0, stream>>>(sums, cnts, lw, lb, out);
}